// Round 2
// baseline (14528.868 us; speedup 1.0000x reference)
//
#include <hip/hip_runtime.h>
#include <cstdint>
#include <cmath>

// LDS column-group swizzle: row r, float4-group g (64-float rows, 16 groups)
#define SWZ(r, g) ((g) ^ (((r) >> 2) & 7))

// ---------------------------------------------------------------------------
// Kernel 1: fused embedding gather + input projections, time-chunked.
// Forward  (dir=0): X[tl][b][j] = emb[b, t0+tl] . w_ih_f[j] + b_f[j]
// Backward (dir=1): X[tl][b][j] = emb[b, 511-(t0+tl)] . w_ih_b[j] + b_b[j]
// (tl = step index within chunk.)
// Tile: 64 (n) x 64 (j), K=256 in 4 chunks of 64. 256 threads, 4x4 micro-tile.
// ---------------------------------------------------------------------------
__global__ __launch_bounds__(256) void proj_kernel(
    const int* __restrict__ word_ids, const float* __restrict__ embed,
    const float* __restrict__ w_ih_f, const float* __restrict__ b_f,
    const float* __restrict__ w_ih_b, const float* __restrict__ b_b,
    float* __restrict__ XF, float* __restrict__ XB, int t0, int lgL)
{
    __shared__ float lds_a[64 * 64];
    __shared__ float lds_b[64 * 64];
    __shared__ int idx[64];

    const int tid = threadIdx.x;
    const int jt  = blockIdx.x;   // 0..15  (j tile)
    const int nt  = blockIdx.y;   // 0..L-1 (n tile; n = b*L + tl)
    const int dir = blockIdx.z;   // 0..1
    const int Lm1 = (1 << lgL) - 1;
    const float* __restrict__ W    = dir ? w_ih_b : w_ih_f;
    const float* __restrict__ bias = dir ? b_b : b_f;
    float* __restrict__ Xout       = dir ? XB : XF;

    if (tid < 64) {
        int n  = nt * 64 + tid;
        int b  = n >> lgL;
        int tl = n & Lm1;
        int tg = dir ? (511 - (t0 + tl)) : (t0 + tl);
        idx[tid] = word_ids[b * 512 + tg];
    }

    const int tx = tid & 15;   // j micro index
    const int ty = tid >> 4;   // n micro index
    float acc[4][4] = {};

    for (int kc = 0; kc < 4; ++kc) {
        __syncthreads();
        #pragma unroll
        for (int ii = 0; ii < 4; ++ii) {
            int flat4 = ii * 256 + tid;       // 0..1023
            int r = flat4 >> 4;
            int g = flat4 & 15;
            int pg = SWZ(r, g);
            float4 av = *(const float4*)&embed[(size_t)idx[r] * 256 + kc * 64 + g * 4];
            *(float4*)&lds_a[r * 64 + pg * 4] = av;
            float4 bv = *(const float4*)&W[(size_t)(jt * 64 + r) * 256 + kc * 64 + g * 4];
            *(float4*)&lds_b[r * 64 + pg * 4] = bv;
        }
        __syncthreads();
        for (int g = 0; g < 16; ++g) {
            float4 a4[4], b4[4];
            #pragma unroll
            for (int i = 0; i < 4; ++i) {
                int ra = ty * 4 + i;
                a4[i] = *(const float4*)&lds_a[ra * 64 + SWZ(ra, g) * 4];
                int rb = tx * 4 + i;
                b4[i] = *(const float4*)&lds_b[rb * 64 + SWZ(rb, g) * 4];
            }
            #pragma unroll
            for (int i = 0; i < 4; ++i)
                #pragma unroll
                for (int u = 0; u < 4; ++u)
                    acc[i][u] += a4[i].x * b4[u].x + a4[i].y * b4[u].y
                               + a4[i].z * b4[u].z + a4[i].w * b4[u].w;
        }
    }

    const int j0 = jt * 64 + tx * 4;
    const float4 bv4 = *(const float4*)&bias[j0];
    #pragma unroll
    for (int i = 0; i < 4; ++i) {
        int n  = nt * 64 + ty * 4 + i;
        int b  = n >> lgL;
        int tl = n & Lm1;
        float4 v = make_float4(acc[i][0] + bv4.x, acc[i][1] + bv4.y,
                               acc[i][2] + bv4.z, acc[i][3] + bv4.w);
        *(float4*)&Xout[((size_t)tl * 64 + b) * 1024 + j0] = v;
    }
}

// ---------------------------------------------------------------------------
// Kernel 2: persistent BiLSTM scan over global steps [t0, t1).
// 16 teams (2 dir x 8 batch-groups of 8), 16 blocks/team, 256 threads/block.
// Block owns 16 hidden units (64 gate rows); w_hh slice in registers.
// h exchanged per step via ping-pong global buffer + per-team counter barrier
// (slot = global t-1, zeroed once per launch). c carried across chunks in
// state_c; h carries over through team_h parity (chunk length even).
// Spin is watchdog-bounded so a residency failure shows as wrong output,
// not a hang.
// ---------------------------------------------------------------------------
__global__ __launch_bounds__(256, 2) void lstm_scan(
    const float* __restrict__ XF, const float* __restrict__ XB,
    const float* __restrict__ w_hh_f, const float* __restrict__ w_hh_b,
    float* __restrict__ hf, float* __restrict__ hb,
    float* __restrict__ team_h, int* __restrict__ bar_all,
    float* __restrict__ state_c, int t0, int t1)
{
    __shared__ float lds_h[8 * 260];           // [b][k], padded
    __shared__ float scr[8 * 4 * 16 * 9];      // [kq][gate][m][b(pad 9)]

    const int blk  = blockIdx.x;      // 0..255
    const int team = blk >> 4;        // 0..15
    const int rank = blk & 15;        // 0..15
    const int dir  = team >> 3;
    const int bg   = team & 7;
    const int B0   = bg * 8;
    const float* __restrict__ X   = dir ? XB : XF;
    const float* __restrict__ Whh = dir ? w_hh_b : w_hh_f;
    float* __restrict__ Hout      = dir ? hb : hf;

    const int tid = threadIdx.x;
    // phase-A tiling: kq (k-eighth) x bt (batch half) x m (hidden unit)
    const int m_a = tid & 15;
    const int bt  = (tid >> 4) & 1;
    const int kq  = tid >> 5;         // 0..7

    // register-resident w_hh slice: rows {g*256 + rank*16 + m_a}, k in [kq*32, kq*32+32)
    float4 wreg[4][8];
    #pragma unroll
    for (int g = 0; g < 4; ++g)
        #pragma unroll
        for (int c8 = 0; c8 < 8; ++c8)
            wreg[g][c8] = *(const float4*)&Whh[(size_t)(g * 256 + rank * 16 + m_a) * 256
                                               + kq * 32 + c8 * 4];

    // phase-B mapping (tid < 128): b = tid/16, m = tid%16 ; c persists in reg
    const int b_p = tid >> 4;
    const int m_p = tid & 15;
    const int sidx = team * 2048 + b_p * 256 + rank * 16 + m_p;
    float c_state = 0.f;
    if (t0 > 0 && tid < 128) c_state = state_c[sidx];

    float* th = team_h + (size_t)team * 4096;  // [parity][b(8)][m(256)]
    int* bar  = bar_all + team * 512;

    for (int t = t0; t < t1; ++t) {
        if (t > 0) {
            if (tid == 0) {
                __threadfence();                       // release own h writes
                atomicAdd(&bar[t - 1], 1);             // device-scope arrival
                int guard = 0;
                while (__hip_atomic_load(&bar[t - 1], __ATOMIC_ACQUIRE,
                                         __HIP_MEMORY_SCOPE_AGENT) < 16) {
                    __builtin_amdgcn_s_sleep(2);
                    if (++guard > (1 << 17)) break;    // watchdog: fail loud, not hung
                }
            }
            __syncthreads();
            const float* src = th + ((t - 1) & 1) * 2048;
            #pragma unroll
            for (int ii = 0; ii < 2; ++ii) {
                int flat4 = ii * 256 + tid;            // 0..511
                int b  = flat4 >> 6;
                int c4 = (flat4 & 63) << 2;
                *(float4*)&lds_h[b * 260 + c4] = *(const float4*)&src[b * 256 + c4];
            }
        } else {
            #pragma unroll
            for (int ii = 0; ii < 2; ++ii) {
                int flat4 = ii * 256 + tid;
                int b  = flat4 >> 6;
                int c4 = (flat4 & 63) << 2;
                *(float4*)&lds_h[b * 260 + c4] = make_float4(0.f, 0.f, 0.f, 0.f);
            }
        }
        __syncthreads();

        // prefetch X for phase B (hidden behind phase A)
        float xg0 = 0.f, xg1 = 0.f, xg2 = 0.f, xg3 = 0.f;
        if (tid < 128) {
            const float* xp = &X[((size_t)(t - t0) * 64 + B0 + b_p) * 1024 + rank * 16 + m_p];
            xg0 = xp[0]; xg1 = xp[256]; xg2 = xp[512]; xg3 = xp[768];
        }

        // phase A: partial dot products over this thread's k-range
        float acc[4][4] = {};
        #pragma unroll
        for (int c8 = 0; c8 < 8; ++c8) {
            float4 h4[4];
            #pragma unroll
            for (int u = 0; u < 4; ++u)
                h4[u] = *(const float4*)&lds_h[(bt * 4 + u) * 260 + kq * 32 + c8 * 4];
            #pragma unroll
            for (int g = 0; g < 4; ++g)
                #pragma unroll
                for (int u = 0; u < 4; ++u)
                    acc[g][u] += wreg[g][c8].x * h4[u].x + wreg[g][c8].y * h4[u].y
                               + wreg[g][c8].z * h4[u].z + wreg[g][c8].w * h4[u].w;
        }
        #pragma unroll
        for (int g = 0; g < 4; ++g)
            #pragma unroll
            for (int u = 0; u < 4; ++u)
                scr[((kq * 4 + g) * 16 + m_a) * 9 + bt * 4 + u] = acc[g][u];
        __syncthreads();

        // phase B: reduce k-partials, nonlinearity, state update
        if (tid < 128) {
            float gate[4];
            #pragma unroll
            for (int g = 0; g < 4; ++g) {
                float s = 0.f;
                #pragma unroll
                for (int q = 0; q < 8; ++q)
                    s += scr[((q * 4 + g) * 16 + m_p) * 9 + b_p];
                gate[g] = s;
            }
            gate[0] += xg0; gate[1] += xg1; gate[2] += xg2; gate[3] += xg3;
            float ig = 1.f / (1.f + expf(-gate[0]));
            float fg = 1.f / (1.f + expf(-gate[1]));
            float gg = tanhf(gate[2]);
            float og = 1.f / (1.f + expf(-gate[3]));
            c_state = fg * c_state + ig * gg;
            float h = og * tanhf(c_state);
            th[(t & 1) * 2048 + b_p * 256 + rank * 16 + m_p] = h;
            int tt = dir ? (511 - t) : t;
            Hout[((size_t)tt * 64 + B0 + b_p) * 256 + rank * 16 + m_p] = h;
        }
        __syncthreads();   // all writes done before next-iter arrival
    }

    if (tid < 128) state_c[sidx] = c_state;   // carry c to next chunk
}

// ---------------------------------------------------------------------------
// Kernel 3: LayerNorm + classifier + argmax. One wave per (b,t).
// ---------------------------------------------------------------------------
__global__ __launch_bounds__(256) void ln_cls_kernel(
    const float* __restrict__ hf, const float* __restrict__ hb,
    const float* __restrict__ gamma, const float* __restrict__ beta,
    const float* __restrict__ cls_w, const float* __restrict__ cls_b,
    float* __restrict__ logits, float* __restrict__ dout)
{
    const int lane = threadIdx.x & 63;
    const int wid  = threadIdx.x >> 6;
    const int pos  = blockIdx.x * 4 + wid;   // 0..32767
    const int b = pos >> 9;
    const int t = pos & 511;

    float4 v0 = *(const float4*)&hf[((size_t)t * 64 + b) * 256 + lane * 4];
    float4 v1 = *(const float4*)&hb[((size_t)t * 64 + b) * 256 + lane * 4];
    float x[8] = {v0.x, v0.y, v0.z, v0.w, v1.x, v1.y, v1.z, v1.w};

    float s = 0.f;
    #pragma unroll
    for (int i = 0; i < 8; ++i) s += x[i];
    #pragma unroll
    for (int off = 32; off > 0; off >>= 1) s += __shfl_xor(s, off, 64);
    float mu = s * (1.f / 512.f);

    float d[8];
    float sq = 0.f;
    #pragma unroll
    for (int i = 0; i < 8; ++i) { d[i] = x[i] - mu; sq += d[i] * d[i]; }
    #pragma unroll
    for (int off = 32; off > 0; off >>= 1) sq += __shfl_xor(sq, off, 64);
    float rs = 1.f / sqrtf(sq * (1.f / 512.f) + 1e-5f);

    float4 g0  = *(const float4*)&gamma[lane * 4];
    float4 g1  = *(const float4*)&gamma[256 + lane * 4];
    float4 be0 = *(const float4*)&beta[lane * 4];
    float4 be1 = *(const float4*)&beta[256 + lane * 4];
    float y[8];
    y[0] = d[0] * rs * g0.x + be0.x; y[1] = d[1] * rs * g0.y + be0.y;
    y[2] = d[2] * rs * g0.z + be0.z; y[3] = d[3] * rs * g0.w + be0.w;
    y[4] = d[4] * rs * g1.x + be1.x; y[5] = d[5] * rs * g1.y + be1.y;
    y[6] = d[6] * rs * g1.z + be1.z; y[7] = d[7] * rs * g1.w + be1.w;

    float lgt[9];
    #pragma unroll
    for (int c = 0; c < 9; ++c) {
        float4 w0 = *(const float4*)&cls_w[c * 512 + lane * 4];
        float4 w1 = *(const float4*)&cls_w[c * 512 + 256 + lane * 4];
        float p = y[0] * w0.x + y[1] * w0.y + y[2] * w0.z + y[3] * w0.w
                + y[4] * w1.x + y[5] * w1.y + y[6] * w1.z + y[7] * w1.w;
        #pragma unroll
        for (int off = 32; off > 0; off >>= 1) p += __shfl_xor(p, off, 64);
        lgt[c] = p + cls_b[c];
    }
    if (lane == 0) {
        int bestc = 0;
        float bestv = lgt[0];
        #pragma unroll
        for (int c = 1; c < 9; ++c)
            if (lgt[c] > bestv) { bestv = lgt[c]; bestc = c; }  // strict >: first max
        dout[1 + pos] = (float)bestc;
        #pragma unroll
        for (int c = 0; c < 9; ++c) logits[(size_t)pos * 9 + c] = lgt[c];
    }
}

// ---------------------------------------------------------------------------
// Kernel 4: CRF numerator + forward algorithm (logZ). One wave per batch row.
// ---------------------------------------------------------------------------
__global__ __launch_bounds__(64) void crf_kernel(
    const float* __restrict__ logits, const int* __restrict__ label_ids,
    const float* __restrict__ crf_start, const float* __restrict__ crf_end,
    const float* __restrict__ crf_trans, float* __restrict__ llh)
{
    __shared__ float Ts[9][12];
    const int b = blockIdx.x;
    const int lane = threadIdx.x;
    if (lane < 81) Ts[lane / 9][lane % 9] = crf_trans[lane];
    __syncthreads();

    const float* __restrict__ em  = &logits[(size_t)b * 512 * 9];
    const int* __restrict__ tags  = &label_ids[b * 512];

    // numerator: gold path score
    float part = 0.f;
    for (int t = lane; t < 512; t += 64) {
        int tg = tags[t];
        part += em[t * 9 + tg];
        if (t < 511) part += Ts[tg][tags[t + 1]];
    }
    #pragma unroll
    for (int off = 32; off > 0; off >>= 1) part += __shfl_xor(part, off, 64);
    float numer = part + crf_start[tags[0]] + crf_end[tags[511]];

    // forward DP, lanes 0..8 = tags
    const int j = (lane < 9) ? lane : 0;
    float alpha = crf_start[j] + em[j];
    for (int t = 1; t < 512; ++t) {
        float av[9];
        float m = -1e30f;
        #pragma unroll
        for (int i = 0; i < 9; ++i) {
            float ai = __shfl(alpha, i, 64);
            av[i] = ai + Ts[i][j];
            m = fmaxf(m, av[i]);
        }
        float ssum = 0.f;
        #pragma unroll
        for (int i = 0; i < 9; ++i) ssum += expf(av[i] - m);
        alpha = m + logf(ssum) + em[t * 9 + j];
    }
    float v = (lane < 9) ? (alpha + crf_end[j]) : -1e30f;
    float mm = v;
    #pragma unroll
    for (int off = 32; off > 0; off >>= 1) mm = fmaxf(mm, __shfl_xor(mm, off, 64));
    float es = (lane < 9) ? expf(v - mm) : 0.f;
    #pragma unroll
    for (int off = 32; off > 0; off >>= 1) es += __shfl_xor(es, off, 64);
    if (lane == 0) llh[b] = numer - (mm + logf(es));
}

// ---------------------------------------------------------------------------
// Kernel 5: loss = -sum_b llh[b]
// ---------------------------------------------------------------------------
__global__ __launch_bounds__(64) void final_reduce(
    const float* __restrict__ llh, float* __restrict__ dout)
{
    float v = llh[threadIdx.x];
    #pragma unroll
    for (int off = 32; off > 0; off >>= 1) v += __shfl_xor(v, off, 64);
    if (threadIdx.x == 0) dout[0] = -v;
}

// ---------------------------------------------------------------------------
extern "C" void kernel_launch(void* const* d_in, const int* in_sizes, int n_in,
                              void* d_out, int out_size, void* d_ws, size_t ws_size,
                              hipStream_t stream)
{
    const int*   word_ids  = (const int*)d_in[0];
    const int*   label_ids = (const int*)d_in[1];
    const float* embed     = (const float*)d_in[2];
    const float* w_ih_f    = (const float*)d_in[3];
    const float* w_hh_f    = (const float*)d_in[4];
    const float* b_f       = (const float*)d_in[5];
    const float* w_ih_b    = (const float*)d_in[6];
    const float* w_hh_b    = (const float*)d_in[7];
    const float* b_b       = (const float*)d_in[8];
    const float* ln_gamma  = (const float*)d_in[9];
    const float* ln_beta   = (const float*)d_in[10];
    const float* cls_w     = (const float*)d_in[11];
    const float* cls_b     = (const float*)d_in[12];
    const float* crf_start = (const float*)d_in[13];
    const float* crf_end   = (const float*)d_in[14];
    const float* crf_trans = (const float*)d_in[15];

    char* w = (char*)d_ws;
    auto alloc = [&](size_t bytes) -> char* {
        char* p = w; w += (bytes + 255) & ~(size_t)255; return p;
    };
    float* hf      = (float*)alloc((size_t)8388608 * 4);   // [512][64][256]
    float* hb      = (float*)alloc((size_t)8388608 * 4);
    float* logits  = (float*)alloc((size_t)294912 * 4);    // [B*T][9]
    float* team_h  = (float*)alloc((size_t)65536 * 4);     // 16 teams x 2 x 8 x 256
    int*   bar     = (int*)  alloc((size_t)8192 * 4);      // 16 teams x 512 slots
    float* state_c = (float*)alloc((size_t)32768 * 4);     // 16 teams x 8 x 256
    float* llh     = (float*)alloc((size_t)64 * 4);
    size_t fixed   = (size_t)(w - (char*)d_ws);

    // choose largest time-chunk L whose X buffers fit in the remaining ws
    int L = 512;
    while (L > 32 && fixed + (size_t)L * 524288 > ws_size) L >>= 1;
    float* XF = (float*)alloc((size_t)L * 65536 * 4);      // [L][64][1024]
    float* XB = (float*)alloc((size_t)L * 65536 * 4);
    int lgL = 31 - __builtin_clz((unsigned)L);

    hipMemsetAsync(bar, 0, 8192 * 4, stream);

    for (int t0 = 0; t0 < 512; t0 += L) {
        proj_kernel<<<dim3(16, L, 2), 256, 0, stream>>>(
            word_ids, embed, w_ih_f, b_f, w_ih_b, b_b, XF, XB, t0, lgL);
        lstm_scan<<<256, 256, 0, stream>>>(
            XF, XB, w_hh_f, w_hh_b, hf, hb, team_h, bar, state_c, t0, t0 + L);
    }
    ln_cls_kernel<<<8192, 256, 0, stream>>>(
        hf, hb, ln_gamma, ln_beta, cls_w, cls_b, logits, (float*)d_out);
    crf_kernel<<<64, 64, 0, stream>>>(
        logits, label_ids, crf_start, crf_end, crf_trans, llh);
    final_reduce<<<1, 64, 0, stream>>>(llh, (float*)d_out);
}

// Round 3
// 10469.514 us; speedup vs baseline: 1.3877x; 1.3877x over previous
//
#include <hip/hip_runtime.h>
#include <cstdint>
#include <cmath>

// LDS column-group swizzle: row r, float4-group g (64-float rows, 16 groups)
#define SWZ(r, g) ((g) ^ (((r) >> 2) & 7))

// ---------------------------------------------------------------------------
// Kernel 1: fused embedding gather + input projections, time-chunked.
// Forward  (dir=0): X[tl][b][j] = emb[b, t0+tl] . w_ih_f[j] + b_f[j]
// Backward (dir=1): X[tl][b][j] = emb[b, 511-(t0+tl)] . w_ih_b[j] + b_b[j]
// ---------------------------------------------------------------------------
__global__ __launch_bounds__(256) void proj_kernel(
    const int* __restrict__ word_ids, const float* __restrict__ embed,
    const float* __restrict__ w_ih_f, const float* __restrict__ b_f,
    const float* __restrict__ w_ih_b, const float* __restrict__ b_b,
    float* __restrict__ XF, float* __restrict__ XB, int t0, int lgL)
{
    __shared__ float lds_a[64 * 64];
    __shared__ float lds_b[64 * 64];
    __shared__ int idx[64];

    const int tid = threadIdx.x;
    const int jt  = blockIdx.x;   // 0..15  (j tile)
    const int nt  = blockIdx.y;   // 0..L-1 (n tile; n = b*L + tl)
    const int dir = blockIdx.z;   // 0..1
    const int Lm1 = (1 << lgL) - 1;
    const float* __restrict__ W    = dir ? w_ih_b : w_ih_f;
    const float* __restrict__ bias = dir ? b_b : b_f;
    float* __restrict__ Xout       = dir ? XB : XF;

    if (tid < 64) {
        int n  = nt * 64 + tid;
        int b  = n >> lgL;
        int tl = n & Lm1;
        int tg = dir ? (511 - (t0 + tl)) : (t0 + tl);
        idx[tid] = word_ids[b * 512 + tg];
    }

    const int tx = tid & 15;   // j micro index
    const int ty = tid >> 4;   // n micro index
    float acc[4][4] = {};

    for (int kc = 0; kc < 4; ++kc) {
        __syncthreads();
        #pragma unroll
        for (int ii = 0; ii < 4; ++ii) {
            int flat4 = ii * 256 + tid;       // 0..1023
            int r = flat4 >> 4;
            int g = flat4 & 15;
            int pg = SWZ(r, g);
            float4 av = *(const float4*)&embed[(size_t)idx[r] * 256 + kc * 64 + g * 4];
            *(float4*)&lds_a[r * 64 + pg * 4] = av;
            float4 bv = *(const float4*)&W[(size_t)(jt * 64 + r) * 256 + kc * 64 + g * 4];
            *(float4*)&lds_b[r * 64 + pg * 4] = bv;
        }
        __syncthreads();
        for (int g = 0; g < 16; ++g) {
            float4 a4[4], b4[4];
            #pragma unroll
            for (int i = 0; i < 4; ++i) {
                int ra = ty * 4 + i;
                a4[i] = *(const float4*)&lds_a[ra * 64 + SWZ(ra, g) * 4];
                int rb = tx * 4 + i;
                b4[i] = *(const float4*)&lds_b[rb * 64 + SWZ(rb, g) * 4];
            }
            #pragma unroll
            for (int i = 0; i < 4; ++i)
                #pragma unroll
                for (int u = 0; u < 4; ++u)
                    acc[i][u] += a4[i].x * b4[u].x + a4[i].y * b4[u].y
                               + a4[i].z * b4[u].z + a4[i].w * b4[u].w;
        }
    }

    const int j0 = jt * 64 + tx * 4;
    const float4 bv4 = *(const float4*)&bias[j0];
    #pragma unroll
    for (int i = 0; i < 4; ++i) {
        int n  = nt * 64 + ty * 4 + i;
        int b  = n >> lgL;
        int tl = n & Lm1;
        float4 v = make_float4(acc[i][0] + bv4.x, acc[i][1] + bv4.y,
                               acc[i][2] + bv4.z, acc[i][3] + bv4.w);
        *(float4*)&Xout[((size_t)tl * 64 + b) * 1024 + j0] = v;
    }
}

// ---------------------------------------------------------------------------
// Kernel 2: persistent BiLSTM scan over global steps [t0, t1).
// 16 teams (2 dir x 8 batch-groups of 8), 16 blocks/team, 256 threads/block.
// Cross-block h exchange uses RELAXED agent-scope atomics only: sc1-scoped
// stores/loads reach the L3 coherence point with NO buffer_wbl2/buffer_inv
// (the acquire/release fences we used before invalidated/wrote back the
// whole XCD L2 per step — 8 GB/dispatch of TCC traffic, VALUBusy 3%).
// Ordering: loop-end __syncthreads() drains vmcnt for all waves (compiler
// emits s_waitcnt vmcnt(0) before s_barrier), so the arrival add issued
// after it is globally ordered behind the h stores.
// ---------------------------------------------------------------------------
__global__ __launch_bounds__(256, 2) void lstm_scan(
    const float* __restrict__ XF, const float* __restrict__ XB,
    const float* __restrict__ w_hh_f, const float* __restrict__ w_hh_b,
    float* __restrict__ hf, float* __restrict__ hb,
    float* __restrict__ team_h, int* __restrict__ bar_all,
    float* __restrict__ state_c, int t0, int t1)
{
    __shared__ float lds_h[8 * 260];           // [b][k], padded
    __shared__ float scr[8 * 4 * 16 * 9];      // [kq][gate][m][b(pad 9)]

    const int blk  = blockIdx.x;      // 0..255
    const int team = blk >> 4;        // 0..15
    const int rank = blk & 15;        // 0..15
    const int dir  = team >> 3;
    const int bg   = team & 7;
    const int B0   = bg * 8;
    const float* __restrict__ X   = dir ? XB : XF;
    const float* __restrict__ Whh = dir ? w_hh_b : w_hh_f;
    float* __restrict__ Hout      = dir ? hb : hf;

    const int tid = threadIdx.x;
    // phase-A tiling: kq (k-eighth) x bt (batch half) x m (hidden unit)
    const int m_a = tid & 15;
    const int bt  = (tid >> 4) & 1;
    const int kq  = tid >> 5;         // 0..7

    // register-resident w_hh slice: rows {g*256 + rank*16 + m_a}, k in [kq*32, kq*32+32)
    float4 wreg[4][8];
    #pragma unroll
    for (int g = 0; g < 4; ++g)
        #pragma unroll
        for (int c8 = 0; c8 < 8; ++c8)
            wreg[g][c8] = *(const float4*)&Whh[(size_t)(g * 256 + rank * 16 + m_a) * 256
                                               + kq * 32 + c8 * 4];

    // phase-B mapping (tid < 128): b = tid/16, m = tid%16 ; c persists in reg
    const int b_p = tid >> 4;
    const int m_p = tid & 15;
    const int sidx = team * 2048 + b_p * 256 + rank * 16 + m_p;
    float c_state = 0.f;
    if (t0 > 0 && tid < 128) c_state = state_c[sidx];

    float* th = team_h + (size_t)team * 4096;  // [parity][b(8)][m(256)]
    int* bar  = bar_all + team * 512;

    for (int t = t0; t < t1; ++t) {
        // X prefetch for phase B — independent of h, in flight during barrier
        float xg0 = 0.f, xg1 = 0.f, xg2 = 0.f, xg3 = 0.f;
        if (tid < 128) {
            const float* xp = &X[((size_t)(t - t0) * 64 + B0 + b_p) * 1024 + rank * 16 + m_p];
            xg0 = xp[0]; xg1 = xp[256]; xg2 = xp[512]; xg3 = xp[768];
        }

        if (t > 0) {
            if (tid == 0) {
                // arrival: h stores for step t-1 were vmcnt-drained by the
                // loop-end __syncthreads (or by prior-dispatch completion)
                __hip_atomic_fetch_add(&bar[t - 1], 1, __ATOMIC_RELAXED,
                                       __HIP_MEMORY_SCOPE_AGENT);
                int guard = 0;
                while (__hip_atomic_load(&bar[t - 1], __ATOMIC_RELAXED,
                                         __HIP_MEMORY_SCOPE_AGENT) < 16) {
                    __builtin_amdgcn_s_sleep(1);
                    if (++guard > (1 << 18)) break;    // watchdog: fail loud, not hung
                }
            }
            __syncthreads();
            const float* src = th + ((t - 1) & 1) * 2048;
            #pragma unroll
            for (int j = 0; j < 8; ++j) {
                int f = j * 256 + tid;                 // b = j, m = tid
                float v = __hip_atomic_load(&src[f], __ATOMIC_RELAXED,
                                            __HIP_MEMORY_SCOPE_AGENT);
                lds_h[j * 260 + tid] = v;
            }
        } else {
            #pragma unroll
            for (int j = 0; j < 8; ++j)
                lds_h[j * 260 + tid] = 0.f;
        }
        __syncthreads();

        // phase A: partial dot products over this thread's k-range
        float acc[4][4] = {};
        #pragma unroll
        for (int c8 = 0; c8 < 8; ++c8) {
            float4 h4[4];
            #pragma unroll
            for (int u = 0; u < 4; ++u)
                h4[u] = *(const float4*)&lds_h[(bt * 4 + u) * 260 + kq * 32 + c8 * 4];
            #pragma unroll
            for (int g = 0; g < 4; ++g)
                #pragma unroll
                for (int u = 0; u < 4; ++u)
                    acc[g][u] += wreg[g][c8].x * h4[u].x + wreg[g][c8].y * h4[u].y
                               + wreg[g][c8].z * h4[u].z + wreg[g][c8].w * h4[u].w;
        }
        #pragma unroll
        for (int g = 0; g < 4; ++g)
            #pragma unroll
            for (int u = 0; u < 4; ++u)
                scr[((kq * 4 + g) * 16 + m_a) * 9 + bt * 4 + u] = acc[g][u];
        __syncthreads();

        // phase B: reduce k-partials, nonlinearity, state update
        if (tid < 128) {
            float gate[4];
            #pragma unroll
            for (int g = 0; g < 4; ++g) {
                float s = 0.f;
                #pragma unroll
                for (int q = 0; q < 8; ++q)
                    s += scr[((q * 4 + g) * 16 + m_p) * 9 + b_p];
                gate[g] = s;
            }
            gate[0] += xg0; gate[1] += xg1; gate[2] += xg2; gate[3] += xg3;
            float ig = 1.f / (1.f + expf(-gate[0]));
            float fg = 1.f / (1.f + expf(-gate[1]));
            float gg = tanhf(gate[2]);
            float og = 1.f / (1.f + expf(-gate[3]));
            c_state = fg * c_state + ig * gg;
            float h = og * tanhf(c_state);
            __hip_atomic_store(&th[(t & 1) * 2048 + b_p * 256 + rank * 16 + m_p], h,
                               __ATOMIC_RELAXED, __HIP_MEMORY_SCOPE_AGENT);
            int tt = dir ? (511 - t) : t;
            Hout[((size_t)tt * 64 + B0 + b_p) * 256 + rank * 16 + m_p] = h;
        }
        __syncthreads();   // drains vmcnt (incl. sc1 h stores) before next arrival
    }

    if (tid < 128) state_c[sidx] = c_state;   // carry c to next chunk
}

// ---------------------------------------------------------------------------
// Kernel 3: LayerNorm + classifier + argmax. One wave per (b,t).
// ---------------------------------------------------------------------------
__global__ __launch_bounds__(256) void ln_cls_kernel(
    const float* __restrict__ hf, const float* __restrict__ hb,
    const float* __restrict__ gamma, const float* __restrict__ beta,
    const float* __restrict__ cls_w, const float* __restrict__ cls_b,
    float* __restrict__ logits, float* __restrict__ dout)
{
    const int lane = threadIdx.x & 63;
    const int wid  = threadIdx.x >> 6;
    const int pos  = blockIdx.x * 4 + wid;   // 0..32767
    const int b = pos >> 9;
    const int t = pos & 511;

    float4 v0 = *(const float4*)&hf[((size_t)t * 64 + b) * 256 + lane * 4];
    float4 v1 = *(const float4*)&hb[((size_t)t * 64 + b) * 256 + lane * 4];
    float x[8] = {v0.x, v0.y, v0.z, v0.w, v1.x, v1.y, v1.z, v1.w};

    float s = 0.f;
    #pragma unroll
    for (int i = 0; i < 8; ++i) s += x[i];
    #pragma unroll
    for (int off = 32; off > 0; off >>= 1) s += __shfl_xor(s, off, 64);
    float mu = s * (1.f / 512.f);

    float d[8];
    float sq = 0.f;
    #pragma unroll
    for (int i = 0; i < 8; ++i) { d[i] = x[i] - mu; sq += d[i] * d[i]; }
    #pragma unroll
    for (int off = 32; off > 0; off >>= 1) sq += __shfl_xor(sq, off, 64);
    float rs = 1.f / sqrtf(sq * (1.f / 512.f) + 1e-5f);

    float4 g0  = *(const float4*)&gamma[lane * 4];
    float4 g1  = *(const float4*)&gamma[256 + lane * 4];
    float4 be0 = *(const float4*)&beta[lane * 4];
    float4 be1 = *(const float4*)&beta[256 + lane * 4];
    float y[8];
    y[0] = d[0] * rs * g0.x + be0.x; y[1] = d[1] * rs * g0.y + be0.y;
    y[2] = d[2] * rs * g0.z + be0.z; y[3] = d[3] * rs * g0.w + be0.w;
    y[4] = d[4] * rs * g1.x + be1.x; y[5] = d[5] * rs * g1.y + be1.y;
    y[6] = d[6] * rs * g1.z + be1.z; y[7] = d[7] * rs * g1.w + be1.w;

    float lgt[9];
    #pragma unroll
    for (int c = 0; c < 9; ++c) {
        float4 w0 = *(const float4*)&cls_w[c * 512 + lane * 4];
        float4 w1 = *(const float4*)&cls_w[c * 512 + 256 + lane * 4];
        float p = y[0] * w0.x + y[1] * w0.y + y[2] * w0.z + y[3] * w0.w
                + y[4] * w1.x + y[5] * w1.y + y[6] * w1.z + y[7] * w1.w;
        #pragma unroll
        for (int off = 32; off > 0; off >>= 1) p += __shfl_xor(p, off, 64);
        lgt[c] = p + cls_b[c];
    }
    if (lane == 0) {
        int bestc = 0;
        float bestv = lgt[0];
        #pragma unroll
        for (int c = 1; c < 9; ++c)
            if (lgt[c] > bestv) { bestv = lgt[c]; bestc = c; }  // strict >: first max
        dout[1 + pos] = (float)bestc;
        #pragma unroll
        for (int c = 0; c < 9; ++c) logits[(size_t)pos * 9 + c] = lgt[c];
    }
}

// ---------------------------------------------------------------------------
// Kernel 4: CRF numerator + forward algorithm (logZ). One wave per batch row.
// ---------------------------------------------------------------------------
__global__ __launch_bounds__(64) void crf_kernel(
    const float* __restrict__ logits, const int* __restrict__ label_ids,
    const float* __restrict__ crf_start, const float* __restrict__ crf_end,
    const float* __restrict__ crf_trans, float* __restrict__ llh)
{
    __shared__ float Ts[9][12];
    const int b = blockIdx.x;
    const int lane = threadIdx.x;
    if (lane < 81) Ts[lane / 9][lane % 9] = crf_trans[lane];
    __syncthreads();

    const float* __restrict__ em  = &logits[(size_t)b * 512 * 9];
    const int* __restrict__ tags  = &label_ids[b * 512];

    // numerator: gold path score
    float part = 0.f;
    for (int t = lane; t < 512; t += 64) {
        int tg = tags[t];
        part += em[t * 9 + tg];
        if (t < 511) part += Ts[tg][tags[t + 1]];
    }
    #pragma unroll
    for (int off = 32; off > 0; off >>= 1) part += __shfl_xor(part, off, 64);
    float numer = part + crf_start[tags[0]] + crf_end[tags[511]];

    // forward DP, lanes 0..8 = tags
    const int j = (lane < 9) ? lane : 0;
    float alpha = crf_start[j] + em[j];
    for (int t = 1; t < 512; ++t) {
        float av[9];
        float m = -1e30f;
        #pragma unroll
        for (int i = 0; i < 9; ++i) {
            float ai = __shfl(alpha, i, 64);
            av[i] = ai + Ts[i][j];
            m = fmaxf(m, av[i]);
        }
        float ssum = 0.f;
        #pragma unroll
        for (int i = 0; i < 9; ++i) ssum += expf(av[i] - m);
        alpha = m + logf(ssum) + em[t * 9 + j];
    }
    float v = (lane < 9) ? (alpha + crf_end[j]) : -1e30f;
    float mm = v;
    #pragma unroll
    for (int off = 32; off > 0; off >>= 1) mm = fmaxf(mm, __shfl_xor(mm, off, 64));
    float es = (lane < 9) ? expf(v - mm) : 0.f;
    #pragma unroll
    for (int off = 32; off > 0; off >>= 1) es += __shfl_xor(es, off, 64);
    if (lane == 0) llh[b] = numer - (mm + logf(es));
}

// ---------------------------------------------------------------------------
// Kernel 5: loss = -sum_b llh[b]
// ---------------------------------------------------------------------------
__global__ __launch_bounds__(64) void final_reduce(
    const float* __restrict__ llh, float* __restrict__ dout)
{
    float v = llh[threadIdx.x];
    #pragma unroll
    for (int off = 32; off > 0; off >>= 1) v += __shfl_xor(v, off, 64);
    if (threadIdx.x == 0) dout[0] = -v;
}

// ---------------------------------------------------------------------------
extern "C" void kernel_launch(void* const* d_in, const int* in_sizes, int n_in,
                              void* d_out, int out_size, void* d_ws, size_t ws_size,
                              hipStream_t stream)
{
    const int*   word_ids  = (const int*)d_in[0];
    const int*   label_ids = (const int*)d_in[1];
    const float* embed     = (const float*)d_in[2];
    const float* w_ih_f    = (const float*)d_in[3];
    const float* w_hh_f    = (const float*)d_in[4];
    const float* b_f       = (const float*)d_in[5];
    const float* w_ih_b    = (const float*)d_in[6];
    const float* w_hh_b    = (const float*)d_in[7];
    const float* b_b       = (const float*)d_in[8];
    const float* ln_gamma  = (const float*)d_in[9];
    const float* ln_beta   = (const float*)d_in[10];
    const float* cls_w     = (const float*)d_in[11];
    const float* cls_b     = (const float*)d_in[12];
    const float* crf_start = (const float*)d_in[13];
    const float* crf_end   = (const float*)d_in[14];
    const float* crf_trans = (const float*)d_in[15];

    char* w = (char*)d_ws;
    auto alloc = [&](size_t bytes) -> char* {
        char* p = w; w += (bytes + 255) & ~(size_t)255; return p;
    };
    float* hf      = (float*)alloc((size_t)8388608 * 4);   // [512][64][256]
    float* hb      = (float*)alloc((size_t)8388608 * 4);
    float* logits  = (float*)alloc((size_t)294912 * 4);    // [B*T][9]
    float* team_h  = (float*)alloc((size_t)65536 * 4);     // 16 teams x 2 x 8 x 256
    int*   bar     = (int*)  alloc((size_t)8192 * 4);      // 16 teams x 512 slots
    float* state_c = (float*)alloc((size_t)32768 * 4);     // 16 teams x 8 x 256
    float* llh     = (float*)alloc((size_t)64 * 4);
    size_t fixed   = (size_t)(w - (char*)d_ws);

    // choose largest time-chunk L whose X buffers fit in the remaining ws
    int L = 512;
    while (L > 32 && fixed + (size_t)L * 524288 > ws_size) L >>= 1;
    float* XF = (float*)alloc((size_t)L * 65536 * 4);      // [L][64][1024]
    float* XB = (float*)alloc((size_t)L * 65536 * 4);
    int lgL = 31 - __builtin_clz((unsigned)L);

    hipMemsetAsync(bar, 0, 8192 * 4, stream);

    for (int t0 = 0; t0 < 512; t0 += L) {
        proj_kernel<<<dim3(16, L, 2), 256, 0, stream>>>(
            word_ids, embed, w_ih_f, b_f, w_ih_b, b_b, XF, XB, t0, lgL);
        lstm_scan<<<256, 256, 0, stream>>>(
            XF, XB, w_hh_f, w_hh_b, hf, hb, team_h, bar, state_c, t0, t0 + L);
    }
    ln_cls_kernel<<<8192, 256, 0, stream>>>(
        hf, hb, ln_gamma, ln_beta, cls_w, cls_b, logits, (float*)d_out);
    crf_kernel<<<64, 64, 0, stream>>>(
        logits, label_ids, crf_start, crf_end, crf_trans, llh);
    final_reduce<<<1, 64, 0, stream>>>(llh, (float*)d_out);
}

// Round 4
// 3729.423 us; speedup vs baseline: 3.8957x; 2.8073x over previous
//
#include <hip/hip_runtime.h>
#include <cstdint>
#include <cmath>

// LDS column-group swizzle: row r, float4-group g (64-float rows, 16 groups)
#define SWZ(r, g) ((g) ^ (((r) >> 2) & 7))

// ---------------------------------------------------------------------------
// Kernel 1: fused embedding gather + input projections, time-chunked.
// Forward  (dir=0): X[tl][b][j] = emb[b, t0+tl] . w_ih_f[j] + b_f[j]
// Backward (dir=1): X[tl][b][j] = emb[b, 511-(t0+tl)] . w_ih_b[j] + b_b[j]
// ---------------------------------------------------------------------------
__global__ __launch_bounds__(256) void proj_kernel(
    const int* __restrict__ word_ids, const float* __restrict__ embed,
    const float* __restrict__ w_ih_f, const float* __restrict__ b_f,
    const float* __restrict__ w_ih_b, const float* __restrict__ b_b,
    float* __restrict__ XF, float* __restrict__ XB, int t0, int lgL)
{
    __shared__ float lds_a[64 * 64];
    __shared__ float lds_b[64 * 64];
    __shared__ int idx[64];

    const int tid = threadIdx.x;
    const int jt  = blockIdx.x;   // 0..15  (j tile)
    const int nt  = blockIdx.y;   // 0..L-1 (n tile; n = b*L + tl)
    const int dir = blockIdx.z;   // 0..1
    const int Lm1 = (1 << lgL) - 1;
    const float* __restrict__ W    = dir ? w_ih_b : w_ih_f;
    const float* __restrict__ bias = dir ? b_b : b_f;
    float* __restrict__ Xout       = dir ? XB : XF;

    if (tid < 64) {
        int n  = nt * 64 + tid;
        int b  = n >> lgL;
        int tl = n & Lm1;
        int tg = dir ? (511 - (t0 + tl)) : (t0 + tl);
        idx[tid] = word_ids[b * 512 + tg];
    }

    const int tx = tid & 15;   // j micro index
    const int ty = tid >> 4;   // n micro index
    float acc[4][4] = {};

    for (int kc = 0; kc < 4; ++kc) {
        __syncthreads();
        #pragma unroll
        for (int ii = 0; ii < 4; ++ii) {
            int flat4 = ii * 256 + tid;       // 0..1023
            int r = flat4 >> 4;
            int g = flat4 & 15;
            int pg = SWZ(r, g);
            float4 av = *(const float4*)&embed[(size_t)idx[r] * 256 + kc * 64 + g * 4];
            *(float4*)&lds_a[r * 64 + pg * 4] = av;
            float4 bv = *(const float4*)&W[(size_t)(jt * 64 + r) * 256 + kc * 64 + g * 4];
            *(float4*)&lds_b[r * 64 + pg * 4] = bv;
        }
        __syncthreads();
        for (int g = 0; g < 16; ++g) {
            float4 a4[4], b4[4];
            #pragma unroll
            for (int i = 0; i < 4; ++i) {
                int ra = ty * 4 + i;
                a4[i] = *(const float4*)&lds_a[ra * 64 + SWZ(ra, g) * 4];
                int rb = tx * 4 + i;
                b4[i] = *(const float4*)&lds_b[rb * 64 + SWZ(rb, g) * 4];
            }
            #pragma unroll
            for (int i = 0; i < 4; ++i)
                #pragma unroll
                for (int u = 0; u < 4; ++u)
                    acc[i][u] += a4[i].x * b4[u].x + a4[i].y * b4[u].y
                               + a4[i].z * b4[u].z + a4[i].w * b4[u].w;
        }
    }

    const int j0 = jt * 64 + tx * 4;
    const float4 bv4 = *(const float4*)&bias[j0];
    #pragma unroll
    for (int i = 0; i < 4; ++i) {
        int n  = nt * 64 + ty * 4 + i;
        int b  = n >> lgL;
        int tl = n & Lm1;
        float4 v = make_float4(acc[i][0] + bv4.x, acc[i][1] + bv4.y,
                               acc[i][2] + bv4.z, acc[i][3] + bv4.w);
        *(float4*)&Xout[((size_t)tl * 64 + b) * 1024 + j0] = v;
    }
}

// ---------------------------------------------------------------------------
// Kernel 2: persistent BiLSTM scan over global steps [t0, t1).
// 16 teams (2 dir x 8 batch-groups of 8), 16 blocks/team, 256 threads/block.
// w_hh slice (128 VGPRs) MUST stay register-resident: launch_bounds(256,1)
// allows up to 512 VGPRs (at (256,2) the compiler capped at 128 and spilled
// wreg to scratch -> 6.5 GB/dispatch of L2-thrashing spill traffic).
// Sync: per-rank monotonic arrival slots (arr[rank] = t+1, relaxed agent
// store -- no serialized RMW queue), waited on by lanes 0-15 of wave 0 with
// one coalesced 64B load + ballot. Ordering: loop-end __syncthreads() makes
// every wave drain vmcnt (h stores acked at coherence point) before any
// thread can issue the signal store.
// ---------------------------------------------------------------------------
__global__ __launch_bounds__(256, 1) void lstm_scan(
    const float* __restrict__ XF, const float* __restrict__ XB,
    const float* __restrict__ w_hh_f, const float* __restrict__ w_hh_b,
    float* __restrict__ hf, float* __restrict__ hb,
    float* __restrict__ team_h, int* __restrict__ bar_all,
    float* __restrict__ state_c, int t0, int t1)
{
    __shared__ float lds_h[8 * 260];           // [b][k], padded
    __shared__ float scr[8 * 4 * 16 * 9];      // [kq][gate][m][b(pad 9)]

    const int blk  = blockIdx.x;      // 0..255
    const int team = blk >> 4;        // 0..15
    const int rank = blk & 15;        // 0..15
    const int dir  = team >> 3;
    const int bg   = team & 7;
    const int B0   = bg * 8;
    const float* __restrict__ X   = dir ? XB : XF;
    const float* __restrict__ Whh = dir ? w_hh_b : w_hh_f;
    float* __restrict__ Hout      = dir ? hb : hf;

    const int tid = threadIdx.x;
    // phase-A tiling: kq (k-eighth) x bt (batch half) x m (hidden unit)
    const int m_a = tid & 15;
    const int bt  = (tid >> 4) & 1;
    const int kq  = tid >> 5;         // 0..7

    // register-resident w_hh slice: rows {g*256 + rank*16 + m_a}, k in [kq*32, kq*32+32)
    float4 wreg[4][8];
    #pragma unroll
    for (int g = 0; g < 4; ++g)
        #pragma unroll
        for (int c8 = 0; c8 < 8; ++c8)
            wreg[g][c8] = *(const float4*)&Whh[(size_t)(g * 256 + rank * 16 + m_a) * 256
                                               + kq * 32 + c8 * 4];

    // phase-B mapping (tid < 128): b = tid/16, m = tid%16 ; c persists in reg
    const int b_p = tid >> 4;
    const int m_p = tid & 15;
    const int sidx = team * 2048 + b_p * 256 + rank * 16 + m_p;
    float c_state = 0.f;
    if (t0 > 0 && tid < 128) c_state = state_c[sidx];

    float* th = team_h + (size_t)team * 4096;  // [parity][b(8)][m(256)]
    int* arr  = bar_all + team * 16;           // per-rank arrival slots

    for (int t = t0; t < t1; ++t) {
        // X prefetch for phase B — independent of h, in flight during barrier
        float xg0 = 0.f, xg1 = 0.f, xg2 = 0.f, xg3 = 0.f;
        if (tid < 128) {
            const float* xp = &X[((size_t)(t - t0) * 64 + B0 + b_p) * 1024 + rank * 16 + m_p];
            xg0 = xp[0]; xg1 = xp[256]; xg2 = xp[512]; xg3 = xp[768];
        }

        if (t > 0) {
            if (tid < 64) {   // wave 0: lane-parallel arrival check (one 64B line)
                int guard = 0;
                for (;;) {
                    int v = (tid < 16)
                        ? __hip_atomic_load(&arr[tid], __ATOMIC_RELAXED,
                                            __HIP_MEMORY_SCOPE_AGENT)
                        : t;
                    unsigned long long bal = __ballot(v >= t);
                    if (bal == ~0ULL) break;
                    __builtin_amdgcn_s_sleep(1);
                    if (++guard > (1 << 16)) break;    // watchdog: fail loud, not hung
                }
            }
            __syncthreads();
            const float* src = th + ((t - 1) & 1) * 2048;
            #pragma unroll
            for (int j = 0; j < 8; ++j) {
                int f = j * 256 + tid;                 // b = j, m = tid
                float v = __hip_atomic_load(&src[f], __ATOMIC_RELAXED,
                                            __HIP_MEMORY_SCOPE_AGENT);
                lds_h[j * 260 + tid] = v;
            }
        } else {
            #pragma unroll
            for (int j = 0; j < 8; ++j)
                lds_h[j * 260 + tid] = 0.f;
        }
        __syncthreads();

        // phase A: partial dot products over this thread's k-range
        float acc[4][4] = {};
        #pragma unroll
        for (int c8 = 0; c8 < 8; ++c8) {
            float4 h4[4];
            #pragma unroll
            for (int u = 0; u < 4; ++u)
                h4[u] = *(const float4*)&lds_h[(bt * 4 + u) * 260 + kq * 32 + c8 * 4];
            #pragma unroll
            for (int g = 0; g < 4; ++g)
                #pragma unroll
                for (int u = 0; u < 4; ++u)
                    acc[g][u] += wreg[g][c8].x * h4[u].x + wreg[g][c8].y * h4[u].y
                               + wreg[g][c8].z * h4[u].z + wreg[g][c8].w * h4[u].w;
        }
        #pragma unroll
        for (int g = 0; g < 4; ++g)
            #pragma unroll
            for (int u = 0; u < 4; ++u)
                scr[((kq * 4 + g) * 16 + m_a) * 9 + bt * 4 + u] = acc[g][u];
        __syncthreads();

        // phase B: reduce k-partials, nonlinearity, state update
        if (tid < 128) {
            float gate[4];
            #pragma unroll
            for (int g = 0; g < 4; ++g) {
                float s = 0.f;
                #pragma unroll
                for (int q = 0; q < 8; ++q)
                    s += scr[((q * 4 + g) * 16 + m_p) * 9 + b_p];
                gate[g] = s;
            }
            gate[0] += xg0; gate[1] += xg1; gate[2] += xg2; gate[3] += xg3;
            float ig = 1.f / (1.f + expf(-gate[0]));
            float fg = 1.f / (1.f + expf(-gate[1]));
            float gg = tanhf(gate[2]);
            float og = 1.f / (1.f + expf(-gate[3]));
            c_state = fg * c_state + ig * gg;
            float h = og * tanhf(c_state);
            __hip_atomic_store(&th[(t & 1) * 2048 + b_p * 256 + rank * 16 + m_p], h,
                               __ATOMIC_RELAXED, __HIP_MEMORY_SCOPE_AGENT);
            int tt = dir ? (511 - t) : t;
            Hout[((size_t)tt * 64 + B0 + b_p) * 256 + rank * 16 + m_p] = h;
        }
        __syncthreads();   // drains vmcnt (incl. sc1 h stores) in every wave
        if (tid == 0)
            __hip_atomic_store(&arr[rank], t + 1, __ATOMIC_RELAXED,
                               __HIP_MEMORY_SCOPE_AGENT);
    }

    if (tid < 128) state_c[sidx] = c_state;   // carry c to next chunk
}

// ---------------------------------------------------------------------------
// Kernel 3: LayerNorm + classifier + argmax. One wave per (b,t).
// ---------------------------------------------------------------------------
__global__ __launch_bounds__(256) void ln_cls_kernel(
    const float* __restrict__ hf, const float* __restrict__ hb,
    const float* __restrict__ gamma, const float* __restrict__ beta,
    const float* __restrict__ cls_w, const float* __restrict__ cls_b,
    float* __restrict__ logits, float* __restrict__ dout)
{
    const int lane = threadIdx.x & 63;
    const int wid  = threadIdx.x >> 6;
    const int pos  = blockIdx.x * 4 + wid;   // 0..32767
    const int b = pos >> 9;
    const int t = pos & 511;

    float4 v0 = *(const float4*)&hf[((size_t)t * 64 + b) * 256 + lane * 4];
    float4 v1 = *(const float4*)&hb[((size_t)t * 64 + b) * 256 + lane * 4];
    float x[8] = {v0.x, v0.y, v0.z, v0.w, v1.x, v1.y, v1.z, v1.w};

    float s = 0.f;
    #pragma unroll
    for (int i = 0; i < 8; ++i) s += x[i];
    #pragma unroll
    for (int off = 32; off > 0; off >>= 1) s += __shfl_xor(s, off, 64);
    float mu = s * (1.f / 512.f);

    float d[8];
    float sq = 0.f;
    #pragma unroll
    for (int i = 0; i < 8; ++i) { d[i] = x[i] - mu; sq += d[i] * d[i]; }
    #pragma unroll
    for (int off = 32; off > 0; off >>= 1) sq += __shfl_xor(sq, off, 64);
    float rs = 1.f / sqrtf(sq * (1.f / 512.f) + 1e-5f);

    float4 g0  = *(const float4*)&gamma[lane * 4];
    float4 g1  = *(const float4*)&gamma[256 + lane * 4];
    float4 be0 = *(const float4*)&beta[lane * 4];
    float4 be1 = *(const float4*)&beta[256 + lane * 4];
    float y[8];
    y[0] = d[0] * rs * g0.x + be0.x; y[1] = d[1] * rs * g0.y + be0.y;
    y[2] = d[2] * rs * g0.z + be0.z; y[3] = d[3] * rs * g0.w + be0.w;
    y[4] = d[4] * rs * g1.x + be1.x; y[5] = d[5] * rs * g1.y + be1.y;
    y[6] = d[6] * rs * g1.z + be1.z; y[7] = d[7] * rs * g1.w + be1.w;

    float lgt[9];
    #pragma unroll
    for (int c = 0; c < 9; ++c) {
        float4 w0 = *(const float4*)&cls_w[c * 512 + lane * 4];
        float4 w1 = *(const float4*)&cls_w[c * 512 + 256 + lane * 4];
        float p = y[0] * w0.x + y[1] * w0.y + y[2] * w0.z + y[3] * w0.w
                + y[4] * w1.x + y[5] * w1.y + y[6] * w1.z + y[7] * w1.w;
        #pragma unroll
        for (int off = 32; off > 0; off >>= 1) p += __shfl_xor(p, off, 64);
        lgt[c] = p + cls_b[c];
    }
    if (lane == 0) {
        int bestc = 0;
        float bestv = lgt[0];
        #pragma unroll
        for (int c = 1; c < 9; ++c)
            if (lgt[c] > bestv) { bestv = lgt[c]; bestc = c; }  // strict >: first max
        dout[1 + pos] = (float)bestc;
        #pragma unroll
        for (int c = 0; c < 9; ++c) logits[(size_t)pos * 9 + c] = lgt[c];
    }
}

// ---------------------------------------------------------------------------
// Kernel 4: CRF numerator + forward algorithm (logZ). One wave per batch row.
// ---------------------------------------------------------------------------
__global__ __launch_bounds__(64) void crf_kernel(
    const float* __restrict__ logits, const int* __restrict__ label_ids,
    const float* __restrict__ crf_start, const float* __restrict__ crf_end,
    const float* __restrict__ crf_trans, float* __restrict__ llh)
{
    __shared__ float Ts[9][12];
    const int b = blockIdx.x;
    const int lane = threadIdx.x;
    if (lane < 81) Ts[lane / 9][lane % 9] = crf_trans[lane];
    __syncthreads();

    const float* __restrict__ em  = &logits[(size_t)b * 512 * 9];
    const int* __restrict__ tags  = &label_ids[b * 512];

    // numerator: gold path score
    float part = 0.f;
    for (int t = lane; t < 512; t += 64) {
        int tg = tags[t];
        part += em[t * 9 + tg];
        if (t < 511) part += Ts[tg][tags[t + 1]];
    }
    #pragma unroll
    for (int off = 32; off > 0; off >>= 1) part += __shfl_xor(part, off, 64);
    float numer = part + crf_start[tags[0]] + crf_end[tags[511]];

    // forward DP, lanes 0..8 = tags
    const int j = (lane < 9) ? lane : 0;
    float alpha = crf_start[j] + em[j];
    for (int t = 1; t < 512; ++t) {
        float av[9];
        float m = -1e30f;
        #pragma unroll
        for (int i = 0; i < 9; ++i) {
            float ai = __shfl(alpha, i, 64);
            av[i] = ai + Ts[i][j];
            m = fmaxf(m, av[i]);
        }
        float ssum = 0.f;
        #pragma unroll
        for (int i = 0; i < 9; ++i) ssum += expf(av[i] - m);
        alpha = m + logf(ssum) + em[t * 9 + j];
    }
    float v = (lane < 9) ? (alpha + crf_end[j]) : -1e30f;
    float mm = v;
    #pragma unroll
    for (int off = 32; off > 0; off >>= 1) mm = fmaxf(mm, __shfl_xor(mm, off, 64));
    float es = (lane < 9) ? expf(v - mm) : 0.f;
    #pragma unroll
    for (int off = 32; off > 0; off >>= 1) es += __shfl_xor(es, off, 64);
    if (lane == 0) llh[b] = numer - (mm + logf(es));
}

// ---------------------------------------------------------------------------
// Kernel 5: loss = -sum_b llh[b]
// ---------------------------------------------------------------------------
__global__ __launch_bounds__(64) void final_reduce(
    const float* __restrict__ llh, float* __restrict__ dout)
{
    float v = llh[threadIdx.x];
    #pragma unroll
    for (int off = 32; off > 0; off >>= 1) v += __shfl_xor(v, off, 64);
    if (threadIdx.x == 0) dout[0] = -v;
}

// ---------------------------------------------------------------------------
extern "C" void kernel_launch(void* const* d_in, const int* in_sizes, int n_in,
                              void* d_out, int out_size, void* d_ws, size_t ws_size,
                              hipStream_t stream)
{
    const int*   word_ids  = (const int*)d_in[0];
    const int*   label_ids = (const int*)d_in[1];
    const float* embed     = (const float*)d_in[2];
    const float* w_ih_f    = (const float*)d_in[3];
    const float* w_hh_f    = (const float*)d_in[4];
    const float* b_f       = (const float*)d_in[5];
    const float* w_ih_b    = (const float*)d_in[6];
    const float* w_hh_b    = (const float*)d_in[7];
    const float* b_b       = (const float*)d_in[8];
    const float* ln_gamma  = (const float*)d_in[9];
    const float* ln_beta   = (const float*)d_in[10];
    const float* cls_w     = (const float*)d_in[11];
    const float* cls_b     = (const float*)d_in[12];
    const float* crf_start = (const float*)d_in[13];
    const float* crf_end   = (const float*)d_in[14];
    const float* crf_trans = (const float*)d_in[15];

    char* w = (char*)d_ws;
    auto alloc = [&](size_t bytes) -> char* {
        char* p = w; w += (bytes + 255) & ~(size_t)255; return p;
    };
    float* hf      = (float*)alloc((size_t)8388608 * 4);   // [512][64][256]
    float* hb      = (float*)alloc((size_t)8388608 * 4);
    float* logits  = (float*)alloc((size_t)294912 * 4);    // [B*T][9]
    float* team_h  = (float*)alloc((size_t)65536 * 4);     // 16 teams x 2 x 8 x 256
    int*   bar     = (int*)  alloc((size_t)256 * 4);       // 16 teams x 16 rank slots
    float* state_c = (float*)alloc((size_t)32768 * 4);     // 16 teams x 8 x 256
    float* llh     = (float*)alloc((size_t)64 * 4);
    size_t fixed   = (size_t)(w - (char*)d_ws);

    // choose largest time-chunk L whose X buffers fit in the remaining ws
    int L = 512;
    while (L > 32 && fixed + (size_t)L * 524288 > ws_size) L >>= 1;
    float* XF = (float*)alloc((size_t)L * 65536 * 4);      // [L][64][1024]
    float* XB = (float*)alloc((size_t)L * 65536 * 4);
    int lgL = 31 - __builtin_clz((unsigned)L);

    hipMemsetAsync(bar, 0, 256 * 4, stream);

    for (int t0 = 0; t0 < 512; t0 += L) {
        proj_kernel<<<dim3(16, L, 2), 256, 0, stream>>>(
            word_ids, embed, w_ih_f, b_f, w_ih_b, b_b, XF, XB, t0, lgL);
        lstm_scan<<<256, 256, 0, stream>>>(
            XF, XB, w_hh_f, w_hh_b, hf, hb, team_h, bar, state_c, t0, t0 + L);
    }
    ln_cls_kernel<<<8192, 256, 0, stream>>>(
        hf, hb, ln_gamma, ln_beta, cls_w, cls_b, logits, (float*)d_out);
    crf_kernel<<<64, 64, 0, stream>>>(
        logits, label_ids, crf_start, crf_end, crf_trans, llh);
    final_reduce<<<1, 64, 0, stream>>>(llh, (float*)d_out);
}

// Round 5
// 2852.815 us; speedup vs baseline: 5.0928x; 1.3073x over previous
//
#include <hip/hip_runtime.h>
#include <cstdint>
#include <cmath>

// LDS column-group swizzle: row r, float4-group g (64-float rows, 16 groups)
#define SWZ(r, g) ((g) ^ (((r) >> 2) & 7))

// ---------------------------------------------------------------------------
// Kernel 1: fused embedding gather + input projections, time-chunked.
// Forward  (dir=0): X[tl][b][j] = emb[b, t0+tl] . w_ih_f[j] + b_f[j]
// Backward (dir=1): X[tl][b][j] = emb[b, 511-(t0+tl)] . w_ih_b[j] + b_b[j]
// ---------------------------------------------------------------------------
__global__ __launch_bounds__(256) void proj_kernel(
    const int* __restrict__ word_ids, const float* __restrict__ embed,
    const float* __restrict__ w_ih_f, const float* __restrict__ b_f,
    const float* __restrict__ w_ih_b, const float* __restrict__ b_b,
    float* __restrict__ XF, float* __restrict__ XB, int t0, int lgL)
{
    __shared__ float lds_a[64 * 64];
    __shared__ float lds_b[64 * 64];
    __shared__ int idx[64];

    const int tid = threadIdx.x;
    const int jt  = blockIdx.x;   // 0..15  (j tile)
    const int nt  = blockIdx.y;   // 0..L-1 (n tile; n = b*L + tl)
    const int dir = blockIdx.z;   // 0..1
    const int Lm1 = (1 << lgL) - 1;
    const float* __restrict__ W    = dir ? w_ih_b : w_ih_f;
    const float* __restrict__ bias = dir ? b_b : b_f;
    float* __restrict__ Xout       = dir ? XB : XF;

    if (tid < 64) {
        int n  = nt * 64 + tid;
        int b  = n >> lgL;
        int tl = n & Lm1;
        int tg = dir ? (511 - (t0 + tl)) : (t0 + tl);
        idx[tid] = word_ids[b * 512 + tg];
    }

    const int tx = tid & 15;   // j micro index
    const int ty = tid >> 4;   // n micro index
    float acc[4][4] = {};

    for (int kc = 0; kc < 4; ++kc) {
        __syncthreads();
        #pragma unroll
        for (int ii = 0; ii < 4; ++ii) {
            int flat4 = ii * 256 + tid;       // 0..1023
            int r = flat4 >> 4;
            int g = flat4 & 15;
            int pg = SWZ(r, g);
            float4 av = *(const float4*)&embed[(size_t)idx[r] * 256 + kc * 64 + g * 4];
            *(float4*)&lds_a[r * 64 + pg * 4] = av;
            float4 bv = *(const float4*)&W[(size_t)(jt * 64 + r) * 256 + kc * 64 + g * 4];
            *(float4*)&lds_b[r * 64 + pg * 4] = bv;
        }
        __syncthreads();
        for (int g = 0; g < 16; ++g) {
            float4 a4[4], b4[4];
            #pragma unroll
            for (int i = 0; i < 4; ++i) {
                int ra = ty * 4 + i;
                a4[i] = *(const float4*)&lds_a[ra * 64 + SWZ(ra, g) * 4];
                int rb = tx * 4 + i;
                b4[i] = *(const float4*)&lds_b[rb * 64 + SWZ(rb, g) * 4];
            }
            #pragma unroll
            for (int i = 0; i < 4; ++i)
                #pragma unroll
                for (int u = 0; u < 4; ++u)
                    acc[i][u] += a4[i].x * b4[u].x + a4[i].y * b4[u].y
                               + a4[i].z * b4[u].z + a4[i].w * b4[u].w;
        }
    }

    const int j0 = jt * 64 + tx * 4;
    const float4 bv4 = *(const float4*)&bias[j0];
    #pragma unroll
    for (int i = 0; i < 4; ++i) {
        int n  = nt * 64 + ty * 4 + i;
        int b  = n >> lgL;
        int tl = n & Lm1;
        float4 v = make_float4(acc[i][0] + bv4.x, acc[i][1] + bv4.y,
                               acc[i][2] + bv4.z, acc[i][3] + bv4.w);
        *(float4*)&Xout[((size_t)tl * 64 + b) * 1024 + j0] = v;
    }
}

// ---------------------------------------------------------------------------
// Kernel 2: persistent BiLSTM scan over global steps [t0, t1).
// 16 teams (2 dir x 8 batch-groups of 8), 16 blocks/team, 256 threads/block.
// launch_bounds(256,1): w_hh slice (128 VGPRs) must stay register-resident.
//
// Sync: DATA-EMBEDDED. Each h element is a 64-bit word {tag = t+1, h bits}
// stored with ONE relaxed agent-scope 8B atomic (single-copy atomic).
// Readers poll the payload: tag match => value valid. No flags, no fences,
// no vmcnt-ordering assumption (this fixes the stale-h race that produced
// absmax=7 in round 4 and halves the sync round trips).
// Overwrite safety: a writer reaches step t only after seeing all tags==t,
// i.e. every rank finished phase B of t-1, i.e. every rank fully consumed
// the (same-parity) slot it is about to overwrite. Tags are monotonic
// (zeroed once per launch) => no ABA across steps/chunks/graph replays.
// ---------------------------------------------------------------------------
__global__ __launch_bounds__(256, 1) void lstm_scan(
    const float* __restrict__ XF, const float* __restrict__ XB,
    const float* __restrict__ w_hh_f, const float* __restrict__ w_hh_b,
    float* __restrict__ hf, float* __restrict__ hb,
    unsigned long long* __restrict__ team_h,
    float* __restrict__ state_c, int t0, int t1)
{
    __shared__ float lds_h[8 * 260];           // [b][k], padded
    __shared__ float scr[8 * 4 * 16 * 9];      // [kq][gate][m][b(pad 9)]

    const int blk  = blockIdx.x;      // 0..255
    const int team = blk >> 4;        // 0..15
    const int rank = blk & 15;        // 0..15
    const int dir  = team >> 3;
    const int bg   = team & 7;
    const int B0   = bg * 8;
    const float* __restrict__ X   = dir ? XB : XF;
    const float* __restrict__ Whh = dir ? w_hh_b : w_hh_f;
    float* __restrict__ Hout      = dir ? hb : hf;

    const int tid = threadIdx.x;
    // phase-A tiling: kq (k-eighth) x bt (batch half) x m (hidden unit)
    const int m_a = tid & 15;
    const int bt  = (tid >> 4) & 1;
    const int kq  = tid >> 5;         // 0..7

    // register-resident w_hh slice: rows {g*256 + rank*16 + m_a}, k in [kq*32, kq*32+32)
    float4 wreg[4][8];
    #pragma unroll
    for (int g = 0; g < 4; ++g)
        #pragma unroll
        for (int c8 = 0; c8 < 8; ++c8)
            wreg[g][c8] = *(const float4*)&Whh[(size_t)(g * 256 + rank * 16 + m_a) * 256
                                               + kq * 32 + c8 * 4];

    // phase-B mapping (tid < 128): b = tid/16, m = tid%16 ; c persists in reg
    const int b_p = tid >> 4;
    const int m_p = tid & 15;
    const int sidx = team * 2048 + b_p * 256 + rank * 16 + m_p;
    float c_state = 0.f;
    if (t0 > 0 && tid < 128) c_state = state_c[sidx];

    unsigned long long* th = team_h + (size_t)team * 4096;  // [parity][b(8)][m(256)]

    for (int t = t0; t < t1; ++t) {
        // X prefetch for phase B — independent of h, in flight during the poll
        float xg0 = 0.f, xg1 = 0.f, xg2 = 0.f, xg3 = 0.f;
        if (tid < 128) {
            const float* xp = &X[((size_t)(t - t0) * 64 + B0 + b_p) * 1024 + rank * 16 + m_p];
            xg0 = xp[0]; xg1 = xp[256]; xg2 = xp[512]; xg3 = xp[768];
        }

        if (t > 0) {
            // poll tagged h words of step t-1 (tag == t), stage into LDS
            const unsigned long long* src = th + ((size_t)((t - 1) & 1)) * 2048;
            unsigned long long v[8];
            #pragma unroll
            for (int j = 0; j < 8; ++j)
                v[j] = __hip_atomic_load(&src[j * 256 + tid], __ATOMIC_RELAXED,
                                         __HIP_MEMORY_SCOPE_AGENT);
            unsigned maskv = 0;
            int guard = 0;
            for (;;) {
                bool all = true;
                #pragma unroll
                for (int j = 0; j < 8; ++j) {
                    if (!((maskv >> j) & 1)) {
                        if ((unsigned)(v[j] >> 32) == (unsigned)t) {
                            maskv |= 1u << j;
                            lds_h[j * 260 + tid] = __uint_as_float((unsigned)v[j]);
                        } else {
                            all = false;
                        }
                    }
                }
                if (all) break;
                if (++guard > (1 << 15)) {   // watchdog: fail loud, not hung
                    #pragma unroll
                    for (int j = 0; j < 8; ++j)
                        if (!((maskv >> j) & 1))
                            lds_h[j * 260 + tid] = __uint_as_float((unsigned)v[j]);
                    break;
                }
                __builtin_amdgcn_s_sleep(1);
                #pragma unroll
                for (int j = 0; j < 8; ++j)
                    if (!((maskv >> j) & 1))
                        v[j] = __hip_atomic_load(&src[j * 256 + tid], __ATOMIC_RELAXED,
                                                 __HIP_MEMORY_SCOPE_AGENT);
            }
        } else {
            #pragma unroll
            for (int j = 0; j < 8; ++j)
                lds_h[j * 260 + tid] = 0.f;
        }
        __syncthreads();   // lds_h fully staged

        // phase A: partial dot products over this thread's k-range
        float acc[4][4] = {};
        #pragma unroll
        for (int c8 = 0; c8 < 8; ++c8) {
            float4 h4[4];
            #pragma unroll
            for (int u = 0; u < 4; ++u)
                h4[u] = *(const float4*)&lds_h[(bt * 4 + u) * 260 + kq * 32 + c8 * 4];
            #pragma unroll
            for (int g = 0; g < 4; ++g)
                #pragma unroll
                for (int u = 0; u < 4; ++u)
                    acc[g][u] += wreg[g][c8].x * h4[u].x + wreg[g][c8].y * h4[u].y
                               + wreg[g][c8].z * h4[u].z + wreg[g][c8].w * h4[u].w;
        }
        #pragma unroll
        for (int g = 0; g < 4; ++g)
            #pragma unroll
            for (int u = 0; u < 4; ++u)
                scr[((kq * 4 + g) * 16 + m_a) * 9 + bt * 4 + u] = acc[g][u];
        __syncthreads();   // scr ready for phase B

        // phase B: reduce k-partials, nonlinearity, state update
        if (tid < 128) {
            float gate[4];
            #pragma unroll
            for (int g = 0; g < 4; ++g) {
                float s = 0.f;
                #pragma unroll
                for (int q = 0; q < 8; ++q)
                    s += scr[((q * 4 + g) * 16 + m_p) * 9 + b_p];
                gate[g] = s;
            }
            gate[0] += xg0; gate[1] += xg1; gate[2] += xg2; gate[3] += xg3;
            float ig = 1.f / (1.f + expf(-gate[0]));
            float fg = 1.f / (1.f + expf(-gate[1]));
            float gg = tanhf(gate[2]);
            float og = 1.f / (1.f + expf(-gate[3]));
            c_state = fg * c_state + ig * gg;
            float h = og * tanhf(c_state);
            unsigned long long pk =
                ((unsigned long long)(unsigned)(t + 1) << 32) | __float_as_uint(h);
            __hip_atomic_store(&th[((size_t)(t & 1)) * 2048 + b_p * 256 + rank * 16 + m_p],
                               pk, __ATOMIC_RELAXED, __HIP_MEMORY_SCOPE_AGENT);
            int tt = dir ? (511 - t) : t;
            Hout[((size_t)tt * 64 + B0 + b_p) * 256 + rank * 16 + m_p] = h;
        }
        // no loop-end barrier needed: next step's poll cannot succeed until
        // this block's phase-B stores (which follow all scr/lds_h reads) are
        // visible, and the post-staging __syncthreads orders LDS overwrite.
    }

    if (tid < 128) state_c[sidx] = c_state;   // carry c to next chunk
}

// ---------------------------------------------------------------------------
// Kernel 3: LayerNorm + classifier + argmax. One wave per (b,t).
// ---------------------------------------------------------------------------
__global__ __launch_bounds__(256) void ln_cls_kernel(
    const float* __restrict__ hf, const float* __restrict__ hb,
    const float* __restrict__ gamma, const float* __restrict__ beta,
    const float* __restrict__ cls_w, const float* __restrict__ cls_b,
    float* __restrict__ logits, float* __restrict__ dout)
{
    const int lane = threadIdx.x & 63;
    const int wid  = threadIdx.x >> 6;
    const int pos  = blockIdx.x * 4 + wid;   // 0..32767
    const int b = pos >> 9;
    const int t = pos & 511;

    float4 v0 = *(const float4*)&hf[((size_t)t * 64 + b) * 256 + lane * 4];
    float4 v1 = *(const float4*)&hb[((size_t)t * 64 + b) * 256 + lane * 4];
    float x[8] = {v0.x, v0.y, v0.z, v0.w, v1.x, v1.y, v1.z, v1.w};

    float s = 0.f;
    #pragma unroll
    for (int i = 0; i < 8; ++i) s += x[i];
    #pragma unroll
    for (int off = 32; off > 0; off >>= 1) s += __shfl_xor(s, off, 64);
    float mu = s * (1.f / 512.f);

    float d[8];
    float sq = 0.f;
    #pragma unroll
    for (int i = 0; i < 8; ++i) { d[i] = x[i] - mu; sq += d[i] * d[i]; }
    #pragma unroll
    for (int off = 32; off > 0; off >>= 1) sq += __shfl_xor(sq, off, 64);
    float rs = 1.f / sqrtf(sq * (1.f / 512.f) + 1e-5f);

    float4 g0  = *(const float4*)&gamma[lane * 4];
    float4 g1  = *(const float4*)&gamma[256 + lane * 4];
    float4 be0 = *(const float4*)&beta[lane * 4];
    float4 be1 = *(const float4*)&beta[256 + lane * 4];
    float y[8];
    y[0] = d[0] * rs * g0.x + be0.x; y[1] = d[1] * rs * g0.y + be0.y;
    y[2] = d[2] * rs * g0.z + be0.z; y[3] = d[3] * rs * g0.w + be0.w;
    y[4] = d[4] * rs * g1.x + be1.x; y[5] = d[5] * rs * g1.y + be1.y;
    y[6] = d[6] * rs * g1.z + be1.z; y[7] = d[7] * rs * g1.w + be1.w;

    float lgt[9];
    #pragma unroll
    for (int c = 0; c < 9; ++c) {
        float4 w0 = *(const float4*)&cls_w[c * 512 + lane * 4];
        float4 w1 = *(const float4*)&cls_w[c * 512 + 256 + lane * 4];
        float p = y[0] * w0.x + y[1] * w0.y + y[2] * w0.z + y[3] * w0.w
                + y[4] * w1.x + y[5] * w1.y + y[6] * w1.z + y[7] * w1.w;
        #pragma unroll
        for (int off = 32; off > 0; off >>= 1) p += __shfl_xor(p, off, 64);
        lgt[c] = p + cls_b[c];
    }
    if (lane == 0) {
        int bestc = 0;
        float bestv = lgt[0];
        #pragma unroll
        for (int c = 1; c < 9; ++c)
            if (lgt[c] > bestv) { bestv = lgt[c]; bestc = c; }  // strict >: first max
        dout[1 + pos] = (float)bestc;
        #pragma unroll
        for (int c = 0; c < 9; ++c) logits[(size_t)pos * 9 + c] = lgt[c];
    }
}

// ---------------------------------------------------------------------------
// Kernel 4: CRF numerator + forward algorithm (logZ). One wave per batch row.
// ---------------------------------------------------------------------------
__global__ __launch_bounds__(64) void crf_kernel(
    const float* __restrict__ logits, const int* __restrict__ label_ids,
    const float* __restrict__ crf_start, const float* __restrict__ crf_end,
    const float* __restrict__ crf_trans, float* __restrict__ llh)
{
    __shared__ float Ts[9][12];
    const int b = blockIdx.x;
    const int lane = threadIdx.x;
    if (lane < 81) Ts[lane / 9][lane % 9] = crf_trans[lane];
    __syncthreads();

    const float* __restrict__ em  = &logits[(size_t)b * 512 * 9];
    const int* __restrict__ tags  = &label_ids[b * 512];

    // numerator: gold path score
    float part = 0.f;
    for (int t = lane; t < 512; t += 64) {
        int tg = tags[t];
        part += em[t * 9 + tg];
        if (t < 511) part += Ts[tg][tags[t + 1]];
    }
    #pragma unroll
    for (int off = 32; off > 0; off >>= 1) part += __shfl_xor(part, off, 64);
    float numer = part + crf_start[tags[0]] + crf_end[tags[511]];

    // forward DP, lanes 0..8 = tags
    const int j = (lane < 9) ? lane : 0;
    float alpha = crf_start[j] + em[j];
    for (int t = 1; t < 512; ++t) {
        float av[9];
        float m = -1e30f;
        #pragma unroll
        for (int i = 0; i < 9; ++i) {
            float ai = __shfl(alpha, i, 64);
            av[i] = ai + Ts[i][j];
            m = fmaxf(m, av[i]);
        }
        float ssum = 0.f;
        #pragma unroll
        for (int i = 0; i < 9; ++i) ssum += expf(av[i] - m);
        alpha = m + logf(ssum) + em[t * 9 + j];
    }
    float v = (lane < 9) ? (alpha + crf_end[j]) : -1e30f;
    float mm = v;
    #pragma unroll
    for (int off = 32; off > 0; off >>= 1) mm = fmaxf(mm, __shfl_xor(mm, off, 64));
    float es = (lane < 9) ? expf(v - mm) : 0.f;
    #pragma unroll
    for (int off = 32; off > 0; off >>= 1) es += __shfl_xor(es, off, 64);
    if (lane == 0) llh[b] = numer - (mm + logf(es));
}

// ---------------------------------------------------------------------------
// Kernel 5: loss = -sum_b llh[b]
// ---------------------------------------------------------------------------
__global__ __launch_bounds__(64) void final_reduce(
    const float* __restrict__ llh, float* __restrict__ dout)
{
    float v = llh[threadIdx.x];
    #pragma unroll
    for (int off = 32; off > 0; off >>= 1) v += __shfl_xor(v, off, 64);
    if (threadIdx.x == 0) dout[0] = -v;
}

// ---------------------------------------------------------------------------
extern "C" void kernel_launch(void* const* d_in, const int* in_sizes, int n_in,
                              void* d_out, int out_size, void* d_ws, size_t ws_size,
                              hipStream_t stream)
{
    const int*   word_ids  = (const int*)d_in[0];
    const int*   label_ids = (const int*)d_in[1];
    const float* embed     = (const float*)d_in[2];
    const float* w_ih_f    = (const float*)d_in[3];
    const float* w_hh_f    = (const float*)d_in[4];
    const float* b_f       = (const float*)d_in[5];
    const float* w_ih_b    = (const float*)d_in[6];
    const float* w_hh_b    = (const float*)d_in[7];
    const float* b_b       = (const float*)d_in[8];
    const float* ln_gamma  = (const float*)d_in[9];
    const float* ln_beta   = (const float*)d_in[10];
    const float* cls_w     = (const float*)d_in[11];
    const float* cls_b     = (const float*)d_in[12];
    const float* crf_start = (const float*)d_in[13];
    const float* crf_end   = (const float*)d_in[14];
    const float* crf_trans = (const float*)d_in[15];

    char* w = (char*)d_ws;
    auto alloc = [&](size_t bytes) -> char* {
        char* p = w; w += (bytes + 255) & ~(size_t)255; return p;
    };
    float* hf      = (float*)alloc((size_t)8388608 * 4);   // [512][64][256]
    float* hb      = (float*)alloc((size_t)8388608 * 4);
    float* logits  = (float*)alloc((size_t)294912 * 4);    // [B*T][9]
    unsigned long long* team_h =
        (unsigned long long*)alloc((size_t)65536 * 8);     // 16 teams x 2 x 8 x 256 tagged
    float* state_c = (float*)alloc((size_t)32768 * 4);     // 16 teams x 8 x 256
    float* llh     = (float*)alloc((size_t)64 * 4);
    size_t fixed   = (size_t)(w - (char*)d_ws);

    // choose largest time-chunk L whose X buffers fit in the remaining ws
    int L = 512;
    while (L > 32 && fixed + (size_t)L * 524288 > ws_size) L >>= 1;
    float* XF = (float*)alloc((size_t)L * 65536 * 4);      // [L][64][1024]
    float* XB = (float*)alloc((size_t)L * 65536 * 4);
    int lgL = 31 - __builtin_clz((unsigned)L);

    // zero tags once per launch (tag 0 != any t+1 in 1..512)
    hipMemsetAsync(team_h, 0, (size_t)65536 * 8, stream);

    for (int t0 = 0; t0 < 512; t0 += L) {
        proj_kernel<<<dim3(16, L, 2), 256, 0, stream>>>(
            word_ids, embed, w_ih_f, b_f, w_ih_b, b_b, XF, XB, t0, lgL);
        lstm_scan<<<256, 256, 0, stream>>>(
            XF, XB, w_hh_f, w_hh_b, hf, hb, team_h, state_c, t0, t0 + L);
    }
    ln_cls_kernel<<<8192, 256, 0, stream>>>(
        hf, hb, ln_gamma, ln_beta, cls_w, cls_b, logits, (float*)d_out);
    crf_kernel<<<64, 64, 0, stream>>>(
        logits, label_ids, crf_start, crf_end, crf_trans, llh);
    final_reduce<<<1, 64, 0, stream>>>(llh, (float*)d_out);
}

// Round 6
// 2514.668 us; speedup vs baseline: 5.7776x; 1.1345x over previous
//
#include <hip/hip_runtime.h>
#include <cstdint>
#include <cmath>

typedef __attribute__((ext_vector_type(8))) short short8;   // 8 bf16 (4 VGPRs)
typedef __attribute__((ext_vector_type(4))) float floatx4;  // MFMA C/D

// round-to-nearest-even fp32->bf16, packed pair -> uint
__device__ __forceinline__ unsigned pk_bf16(float x, float y) {
    unsigned ux = __float_as_uint(x); ux = ux + 0x7fffu + ((ux >> 16) & 1u);
    unsigned uy = __float_as_uint(y); uy = uy + 0x7fffu + ((uy >> 16) & 1u);
    return (ux >> 16) | (uy & 0xffff0000u);
}

// ---------------------------------------------------------------------------
// Kernel 1: fused embedding gather + input projections via bf16 MFMA.
// X[tl][b][j] = emb_row . w_ih[j] + b[j], tile 64(n) x 64(j), K=256 staged
// whole in LDS as bf16 (RNE-converted). mfma_f32_16x16x32_bf16:
//   A[m=lane&15][k=(lane>>4)*8+i], B[k=(lane>>4)*8+i][n=lane&15],
//   C/D col=lane&15, row=(lane>>4)*4+reg  (HW-verified mapping).
// ---------------------------------------------------------------------------
__global__ __launch_bounds__(256) void proj_kernel(
    const int* __restrict__ word_ids, const float* __restrict__ embed,
    const float* __restrict__ w_ih_f, const float* __restrict__ b_f,
    const float* __restrict__ w_ih_b, const float* __restrict__ b_b,
    float* __restrict__ XF, float* __restrict__ XB, int t0, int lgL)
{
    __shared__ unsigned short As[64][264];   // 64 x 256 bf16, +8 pad (528B rows)
    __shared__ unsigned short Bs[64][264];
    __shared__ int idx[64];

    const int tid = threadIdx.x;
    const int jt  = blockIdx.x;   // 0..15  (j tile)
    const int nt  = blockIdx.y;   // 0..L-1 (n tile; n = b*L + tl)
    const int dir = blockIdx.z;   // 0..1
    const int Lm1 = (1 << lgL) - 1;
    const float* __restrict__ W    = dir ? w_ih_b : w_ih_f;
    const float* __restrict__ bias = dir ? b_b : b_f;
    float* __restrict__ Xout       = dir ? XB : XF;

    if (tid < 64) {
        int n  = nt * 64 + tid;
        int b  = n >> lgL;
        int tl = n & Lm1;
        int tg = dir ? (511 - (t0 + tl)) : (t0 + tl);
        idx[tid] = word_ids[b * 512 + tg];
    }
    __syncthreads();

    // stage + convert both tiles: each thread 16 float4 of A and of B
    #pragma unroll
    for (int i = 0; i < 16; ++i) {
        int flat = i * 256 + tid;        // 0..4095 float4 units
        int r  = flat >> 6;              // row 0..63
        int kq = flat & 63;              // k = kq*4
        floatx4 a = *(const floatx4*)&embed[(size_t)idx[r] * 256 + kq * 4];
        *(uint2*)&As[r][kq * 4] = make_uint2(pk_bf16(a.x, a.y), pk_bf16(a.z, a.w));
        floatx4 wv = *(const floatx4*)&W[(size_t)(jt * 64 + r) * 256 + kq * 4];
        *(uint2*)&Bs[r][kq * 4] = make_uint2(pk_bf16(wv.x, wv.y), pk_bf16(wv.z, wv.w));
    }
    __syncthreads();

    const int w    = tid >> 6;     // wave 0..3: n-rows [w*16, w*16+16)
    const int lane = tid & 63;
    const int q    = lane >> 4;    // k-quad
    const int lr   = lane & 15;

    // A-fragments: 8 k-steps, reused across all 4 j-tiles
    short8 af[8];
    #pragma unroll
    for (int ks = 0; ks < 8; ++ks)
        af[ks] = *(const short8*)&As[w * 16 + lr][ks * 32 + q * 8];

    floatx4 acc[4];
    #pragma unroll
    for (int jt4 = 0; jt4 < 4; ++jt4) {
        floatx4 c = {0.f, 0.f, 0.f, 0.f};
        #pragma unroll
        for (int ks = 0; ks < 8; ++ks) {
            short8 bf = *(const short8*)&Bs[jt4 * 16 + lr][ks * 32 + q * 8];
            c = __builtin_amdgcn_mfma_f32_16x16x32_bf16(af[ks], bf, c, 0, 0, 0);
        }
        acc[jt4] = c;
    }

    // epilogue: bias + scatter to X[tl][b][j]
    #pragma unroll
    for (int jt4 = 0; jt4 < 4; ++jt4) {
        int j = jt * 64 + jt4 * 16 + lr;
        float bj = bias[j];
        #pragma unroll
        for (int reg = 0; reg < 4; ++reg) {
            int n  = nt * 64 + w * 16 + q * 4 + reg;
            int b  = n >> lgL;
            int tl = n & Lm1;
            Xout[((size_t)tl * 64 + b) * 1024 + j] = acc[jt4][reg] + bj;
        }
    }
}

// ---------------------------------------------------------------------------
// Kernel 2: persistent BiLSTM scan over global steps [t0, t1).
// (unchanged from round 5 — data-embedded tag sync, absmax 0.0)
// ---------------------------------------------------------------------------
__global__ __launch_bounds__(256, 1) void lstm_scan(
    const float* __restrict__ XF, const float* __restrict__ XB,
    const float* __restrict__ w_hh_f, const float* __restrict__ w_hh_b,
    float* __restrict__ hf, float* __restrict__ hb,
    unsigned long long* __restrict__ team_h,
    float* __restrict__ state_c, int t0, int t1)
{
    __shared__ float lds_h[8 * 260];           // [b][k], padded
    __shared__ float scr[8 * 4 * 16 * 9];      // [kq][gate][m][b(pad 9)]

    const int blk  = blockIdx.x;      // 0..255
    const int team = blk >> 4;        // 0..15
    const int rank = blk & 15;        // 0..15
    const int dir  = team >> 3;
    const int bg   = team & 7;
    const int B0   = bg * 8;
    const float* __restrict__ X   = dir ? XB : XF;
    const float* __restrict__ Whh = dir ? w_hh_b : w_hh_f;
    float* __restrict__ Hout      = dir ? hb : hf;

    const int tid = threadIdx.x;
    const int m_a = tid & 15;
    const int bt  = (tid >> 4) & 1;
    const int kq  = tid >> 5;         // 0..7

    float4 wreg[4][8];
    #pragma unroll
    for (int g = 0; g < 4; ++g)
        #pragma unroll
        for (int c8 = 0; c8 < 8; ++c8)
            wreg[g][c8] = *(const float4*)&Whh[(size_t)(g * 256 + rank * 16 + m_a) * 256
                                               + kq * 32 + c8 * 4];

    const int b_p = tid >> 4;
    const int m_p = tid & 15;
    const int sidx = team * 2048 + b_p * 256 + rank * 16 + m_p;
    float c_state = 0.f;
    if (t0 > 0 && tid < 128) c_state = state_c[sidx];

    unsigned long long* th = team_h + (size_t)team * 4096;  // [parity][b(8)][m(256)]

    for (int t = t0; t < t1; ++t) {
        float xg0 = 0.f, xg1 = 0.f, xg2 = 0.f, xg3 = 0.f;
        if (tid < 128) {
            const float* xp = &X[((size_t)(t - t0) * 64 + B0 + b_p) * 1024 + rank * 16 + m_p];
            xg0 = xp[0]; xg1 = xp[256]; xg2 = xp[512]; xg3 = xp[768];
        }

        if (t > 0) {
            const unsigned long long* src = th + ((size_t)((t - 1) & 1)) * 2048;
            unsigned long long v[8];
            #pragma unroll
            for (int j = 0; j < 8; ++j)
                v[j] = __hip_atomic_load(&src[j * 256 + tid], __ATOMIC_RELAXED,
                                         __HIP_MEMORY_SCOPE_AGENT);
            unsigned maskv = 0;
            int guard = 0;
            for (;;) {
                bool all = true;
                #pragma unroll
                for (int j = 0; j < 8; ++j) {
                    if (!((maskv >> j) & 1)) {
                        if ((unsigned)(v[j] >> 32) == (unsigned)t) {
                            maskv |= 1u << j;
                            lds_h[j * 260 + tid] = __uint_as_float((unsigned)v[j]);
                        } else {
                            all = false;
                        }
                    }
                }
                if (all) break;
                if (++guard > (1 << 15)) {
                    #pragma unroll
                    for (int j = 0; j < 8; ++j)
                        if (!((maskv >> j) & 1))
                            lds_h[j * 260 + tid] = __uint_as_float((unsigned)v[j]);
                    break;
                }
                __builtin_amdgcn_s_sleep(1);
                #pragma unroll
                for (int j = 0; j < 8; ++j)
                    if (!((maskv >> j) & 1))
                        v[j] = __hip_atomic_load(&src[j * 256 + tid], __ATOMIC_RELAXED,
                                                 __HIP_MEMORY_SCOPE_AGENT);
            }
        } else {
            #pragma unroll
            for (int j = 0; j < 8; ++j)
                lds_h[j * 260 + tid] = 0.f;
        }
        __syncthreads();

        float acc[4][4] = {};
        #pragma unroll
        for (int c8 = 0; c8 < 8; ++c8) {
            float4 h4[4];
            #pragma unroll
            for (int u = 0; u < 4; ++u)
                h4[u] = *(const float4*)&lds_h[(bt * 4 + u) * 260 + kq * 32 + c8 * 4];
            #pragma unroll
            for (int g = 0; g < 4; ++g)
                #pragma unroll
                for (int u = 0; u < 4; ++u)
                    acc[g][u] += wreg[g][c8].x * h4[u].x + wreg[g][c8].y * h4[u].y
                               + wreg[g][c8].z * h4[u].z + wreg[g][c8].w * h4[u].w;
        }
        #pragma unroll
        for (int g = 0; g < 4; ++g)
            #pragma unroll
            for (int u = 0; u < 4; ++u)
                scr[((kq * 4 + g) * 16 + m_a) * 9 + bt * 4 + u] = acc[g][u];
        __syncthreads();

        if (tid < 128) {
            float gate[4];
            #pragma unroll
            for (int g = 0; g < 4; ++g) {
                float s = 0.f;
                #pragma unroll
                for (int q = 0; q < 8; ++q)
                    s += scr[((q * 4 + g) * 16 + m_p) * 9 + b_p];
                gate[g] = s;
            }
            gate[0] += xg0; gate[1] += xg1; gate[2] += xg2; gate[3] += xg3;
            float ig = 1.f / (1.f + expf(-gate[0]));
            float fg = 1.f / (1.f + expf(-gate[1]));
            float gg = tanhf(gate[2]);
            float og = 1.f / (1.f + expf(-gate[3]));
            c_state = fg * c_state + ig * gg;
            float h = og * tanhf(c_state);
            unsigned long long pk =
                ((unsigned long long)(unsigned)(t + 1) << 32) | __float_as_uint(h);
            __hip_atomic_store(&th[((size_t)(t & 1)) * 2048 + b_p * 256 + rank * 16 + m_p],
                               pk, __ATOMIC_RELAXED, __HIP_MEMORY_SCOPE_AGENT);
            int tt = dir ? (511 - t) : t;
            Hout[((size_t)tt * 64 + B0 + b_p) * 256 + rank * 16 + m_p] = h;
        }
    }

    if (tid < 128) state_c[sidx] = c_state;
}

// ---------------------------------------------------------------------------
// Kernel 3: LayerNorm + classifier + argmax. One wave per (b,t).
// ---------------------------------------------------------------------------
__global__ __launch_bounds__(256) void ln_cls_kernel(
    const float* __restrict__ hf, const float* __restrict__ hb,
    const float* __restrict__ gamma, const float* __restrict__ beta,
    const float* __restrict__ cls_w, const float* __restrict__ cls_b,
    float* __restrict__ logits, float* __restrict__ dout)
{
    const int lane = threadIdx.x & 63;
    const int wid  = threadIdx.x >> 6;
    const int pos  = blockIdx.x * 4 + wid;   // 0..32767
    const int b = pos >> 9;
    const int t = pos & 511;

    float4 v0 = *(const float4*)&hf[((size_t)t * 64 + b) * 256 + lane * 4];
    float4 v1 = *(const float4*)&hb[((size_t)t * 64 + b) * 256 + lane * 4];
    float x[8] = {v0.x, v0.y, v0.z, v0.w, v1.x, v1.y, v1.z, v1.w};

    float s = 0.f;
    #pragma unroll
    for (int i = 0; i < 8; ++i) s += x[i];
    #pragma unroll
    for (int off = 32; off > 0; off >>= 1) s += __shfl_xor(s, off, 64);
    float mu = s * (1.f / 512.f);

    float d[8];
    float sq = 0.f;
    #pragma unroll
    for (int i = 0; i < 8; ++i) { d[i] = x[i] - mu; sq += d[i] * d[i]; }
    #pragma unroll
    for (int off = 32; off > 0; off >>= 1) sq += __shfl_xor(sq, off, 64);
    float rs = 1.f / sqrtf(sq * (1.f / 512.f) + 1e-5f);

    float4 g0  = *(const float4*)&gamma[lane * 4];
    float4 g1  = *(const float4*)&gamma[256 + lane * 4];
    float4 be0 = *(const float4*)&beta[lane * 4];
    float4 be1 = *(const float4*)&beta[256 + lane * 4];
    float y[8];
    y[0] = d[0] * rs * g0.x + be0.x; y[1] = d[1] * rs * g0.y + be0.y;
    y[2] = d[2] * rs * g0.z + be0.z; y[3] = d[3] * rs * g0.w + be0.w;
    y[4] = d[4] * rs * g1.x + be1.x; y[5] = d[5] * rs * g1.y + be1.y;
    y[6] = d[6] * rs * g1.z + be1.z; y[7] = d[7] * rs * g1.w + be1.w;

    float lgt[9];
    #pragma unroll
    for (int c = 0; c < 9; ++c) {
        float4 w0 = *(const float4*)&cls_w[c * 512 + lane * 4];
        float4 w1 = *(const float4*)&cls_w[c * 512 + 256 + lane * 4];
        float p = y[0] * w0.x + y[1] * w0.y + y[2] * w0.z + y[3] * w0.w
                + y[4] * w1.x + y[5] * w1.y + y[6] * w1.z + y[7] * w1.w;
        #pragma unroll
        for (int off = 32; off > 0; off >>= 1) p += __shfl_xor(p, off, 64);
        lgt[c] = p + cls_b[c];
    }
    if (lane == 0) {
        int bestc = 0;
        float bestv = lgt[0];
        #pragma unroll
        for (int c = 1; c < 9; ++c)
            if (lgt[c] > bestv) { bestv = lgt[c]; bestc = c; }  // strict >: first max
        dout[1 + pos] = (float)bestc;
        #pragma unroll
        for (int c = 0; c < 9; ++c) logits[(size_t)pos * 9 + c] = lgt[c];
    }
}

// ---------------------------------------------------------------------------
// Kernel 4: CRF numerator + forward algorithm (logZ). One wave per batch row.
// ---------------------------------------------------------------------------
__global__ __launch_bounds__(64) void crf_kernel(
    const float* __restrict__ logits, const int* __restrict__ label_ids,
    const float* __restrict__ crf_start, const float* __restrict__ crf_end,
    const float* __restrict__ crf_trans, float* __restrict__ llh)
{
    __shared__ float Ts[9][12];
    const int b = blockIdx.x;
    const int lane = threadIdx.x;
    if (lane < 81) Ts[lane / 9][lane % 9] = crf_trans[lane];
    __syncthreads();

    const float* __restrict__ em  = &logits[(size_t)b * 512 * 9];
    const int* __restrict__ tags  = &label_ids[b * 512];

    float part = 0.f;
    for (int t = lane; t < 512; t += 64) {
        int tg = tags[t];
        part += em[t * 9 + tg];
        if (t < 511) part += Ts[tg][tags[t + 1]];
    }
    #pragma unroll
    for (int off = 32; off > 0; off >>= 1) part += __shfl_xor(part, off, 64);
    float numer = part + crf_start[tags[0]] + crf_end[tags[511]];

    const int j = (lane < 9) ? lane : 0;
    float alpha = crf_start[j] + em[j];
    for (int t = 1; t < 512; ++t) {
        float av[9];
        float m = -1e30f;
        #pragma unroll
        for (int i = 0; i < 9; ++i) {
            float ai = __shfl(alpha, i, 64);
            av[i] = ai + Ts[i][j];
            m = fmaxf(m, av[i]);
        }
        float ssum = 0.f;
        #pragma unroll
        for (int i = 0; i < 9; ++i) ssum += expf(av[i] - m);
        alpha = m + logf(ssum) + em[t * 9 + j];
    }
    float v = (lane < 9) ? (alpha + crf_end[j]) : -1e30f;
    float mm = v;
    #pragma unroll
    for (int off = 32; off > 0; off >>= 1) mm = fmaxf(mm, __shfl_xor(mm, off, 64));
    float es = (lane < 9) ? expf(v - mm) : 0.f;
    #pragma unroll
    for (int off = 32; off > 0; off >>= 1) es += __shfl_xor(es, off, 64);
    if (lane == 0) llh[b] = numer - (mm + logf(es));
}

// ---------------------------------------------------------------------------
// Kernel 5: loss = -sum_b llh[b]
// ---------------------------------------------------------------------------
__global__ __launch_bounds__(64) void final_reduce(
    const float* __restrict__ llh, float* __restrict__ dout)
{
    float v = llh[threadIdx.x];
    #pragma unroll
    for (int off = 32; off > 0; off >>= 1) v += __shfl_xor(v, off, 64);
    if (threadIdx.x == 0) dout[0] = -v;
}

// ---------------------------------------------------------------------------
extern "C" void kernel_launch(void* const* d_in, const int* in_sizes, int n_in,
                              void* d_out, int out_size, void* d_ws, size_t ws_size,
                              hipStream_t stream)
{
    const int*   word_ids  = (const int*)d_in[0];
    const int*   label_ids = (const int*)d_in[1];
    const float* embed     = (const float*)d_in[2];
    const float* w_ih_f    = (const float*)d_in[3];
    const float* w_hh_f    = (const float*)d_in[4];
    const float* b_f       = (const float*)d_in[5];
    const float* w_ih_b    = (const float*)d_in[6];
    const float* w_hh_b    = (const float*)d_in[7];
    const float* b_b       = (const float*)d_in[8];
    const float* ln_gamma  = (const float*)d_in[9];
    const float* ln_beta   = (const float*)d_in[10];
    const float* cls_w     = (const float*)d_in[11];
    const float* cls_b     = (const float*)d_in[12];
    const float* crf_start = (const float*)d_in[13];
    const float* crf_end   = (const float*)d_in[14];
    const float* crf_trans = (const float*)d_in[15];

    char* w = (char*)d_ws;
    auto alloc = [&](size_t bytes) -> char* {
        char* p = w; w += (bytes + 255) & ~(size_t)255; return p;
    };
    float* hf      = (float*)alloc((size_t)8388608 * 4);   // [512][64][256]
    float* hb      = (float*)alloc((size_t)8388608 * 4);
    float* logits  = (float*)alloc((size_t)294912 * 4);    // [B*T][9]
    unsigned long long* team_h =
        (unsigned long long*)alloc((size_t)65536 * 8);     // 16 teams x 2 x 8 x 256 tagged
    float* state_c = (float*)alloc((size_t)32768 * 4);     // 16 teams x 8 x 256
    float* llh     = (float*)alloc((size_t)64 * 4);
    size_t fixed   = (size_t)(w - (char*)d_ws);

    // choose largest time-chunk L whose X buffers fit in the remaining ws
    int L = 512;
    while (L > 32 && fixed + (size_t)L * 524288 > ws_size) L >>= 1;
    float* XF = (float*)alloc((size_t)L * 65536 * 4);      // [L][64][1024]
    float* XB = (float*)alloc((size_t)L * 65536 * 4);
    int lgL = 31 - __builtin_clz((unsigned)L);

    // zero tags once per launch (tag 0 != any t+1 in 1..512)
    hipMemsetAsync(team_h, 0, (size_t)65536 * 8, stream);

    for (int t0 = 0; t0 < 512; t0 += L) {
        proj_kernel<<<dim3(16, L, 2), 256, 0, stream>>>(
            word_ids, embed, w_ih_f, b_f, w_ih_b, b_b, XF, XB, t0, lgL);
        lstm_scan<<<256, 256, 0, stream>>>(
            XF, XB, w_hh_f, w_hh_b, hf, hb, team_h, state_c, t0, t0 + L);
    }
    ln_cls_kernel<<<8192, 256, 0, stream>>>(
        hf, hb, ln_gamma, ln_beta, cls_w, cls_b, logits, (float*)d_out);
    crf_kernel<<<64, 64, 0, stream>>>(
        logits, label_ids, crf_start, crf_end, crf_trans, llh);
    final_reduce<<<1, 64, 0, stream>>>(llh, (float*)d_out);
}

// Round 7
// 1918.529 us; speedup vs baseline: 7.5729x; 1.3107x over previous
//
#include <hip/hip_runtime.h>
#include <cstdint>
#include <cmath>

typedef __attribute__((ext_vector_type(8))) short short8;   // 8 bf16 (4 VGPRs)
typedef __attribute__((ext_vector_type(4))) float floatx4;  // MFMA C/D

// round-to-nearest-even fp32->bf16, packed pair -> uint (lo = x, hi = y)
__device__ __forceinline__ unsigned pk_bf16(float x, float y) {
    unsigned ux = __float_as_uint(x); ux = ux + 0x7fffu + ((ux >> 16) & 1u);
    unsigned uy = __float_as_uint(y); uy = uy + 0x7fffu + ((uy >> 16) & 1u);
    return (ux >> 16) | (uy & 0xffff0000u);
}

// ---------------------------------------------------------------------------
// Kernel 1: fused embedding gather + input projections via bf16 MFMA.
// (unchanged from round 6 — validated)
// ---------------------------------------------------------------------------
__global__ __launch_bounds__(256) void proj_kernel(
    const int* __restrict__ word_ids, const float* __restrict__ embed,
    const float* __restrict__ w_ih_f, const float* __restrict__ b_f,
    const float* __restrict__ w_ih_b, const float* __restrict__ b_b,
    float* __restrict__ XF, float* __restrict__ XB, int t0, int lgL)
{
    __shared__ unsigned short As[64][264];   // 64 x 256 bf16, +8 pad (528B rows)
    __shared__ unsigned short Bs[64][264];
    __shared__ int idx[64];

    const int tid = threadIdx.x;
    const int jt  = blockIdx.x;   // 0..15  (j tile)
    const int nt  = blockIdx.y;   // 0..L-1 (n tile; n = b*L + tl)
    const int dir = blockIdx.z;   // 0..1
    const int Lm1 = (1 << lgL) - 1;
    const float* __restrict__ W    = dir ? w_ih_b : w_ih_f;
    const float* __restrict__ bias = dir ? b_b : b_f;
    float* __restrict__ Xout       = dir ? XB : XF;

    if (tid < 64) {
        int n  = nt * 64 + tid;
        int b  = n >> lgL;
        int tl = n & Lm1;
        int tg = dir ? (511 - (t0 + tl)) : (t0 + tl);
        idx[tid] = word_ids[b * 512 + tg];
    }
    __syncthreads();

    #pragma unroll
    for (int i = 0; i < 16; ++i) {
        int flat = i * 256 + tid;        // 0..4095 float4 units
        int r  = flat >> 6;              // row 0..63
        int kq = flat & 63;              // k = kq*4
        floatx4 a = *(const floatx4*)&embed[(size_t)idx[r] * 256 + kq * 4];
        *(uint2*)&As[r][kq * 4] = make_uint2(pk_bf16(a.x, a.y), pk_bf16(a.z, a.w));
        floatx4 wv = *(const floatx4*)&W[(size_t)(jt * 64 + r) * 256 + kq * 4];
        *(uint2*)&Bs[r][kq * 4] = make_uint2(pk_bf16(wv.x, wv.y), pk_bf16(wv.z, wv.w));
    }
    __syncthreads();

    const int w    = tid >> 6;     // wave 0..3: n-rows [w*16, w*16+16)
    const int lane = tid & 63;
    const int q    = lane >> 4;    // k-quad
    const int lr   = lane & 15;

    short8 af[8];
    #pragma unroll
    for (int ks = 0; ks < 8; ++ks)
        af[ks] = *(const short8*)&As[w * 16 + lr][ks * 32 + q * 8];

    floatx4 acc[4];
    #pragma unroll
    for (int jt4 = 0; jt4 < 4; ++jt4) {
        floatx4 c = {0.f, 0.f, 0.f, 0.f};
        #pragma unroll
        for (int ks = 0; ks < 8; ++ks) {
            short8 bf = *(const short8*)&Bs[jt4 * 16 + lr][ks * 32 + q * 8];
            c = __builtin_amdgcn_mfma_f32_16x16x32_bf16(af[ks], bf, c, 0, 0, 0);
        }
        acc[jt4] = c;
    }

    #pragma unroll
    for (int jt4 = 0; jt4 < 4; ++jt4) {
        int j = jt * 64 + jt4 * 16 + lr;
        float bj = bias[j];
        #pragma unroll
        for (int reg = 0; reg < 4; ++reg) {
            int n  = nt * 64 + w * 16 + q * 4 + reg;
            int b  = n >> lgL;
            int tl = n & Lm1;
            Xout[((size_t)tl * 64 + b) * 1024 + j] = acc[jt4][reg] + bj;
        }
    }
}

// ---------------------------------------------------------------------------
// Kernel 2: persistent BiLSTM scan, MFMA phase A.
// 16 teams (2 dir x 8 batch-groups of 8), 4 ranks/team (64 units each),
// 64 blocks total. W_hh slice held as bf16 MFMA B-fragments in registers
// (128 VGPR/thread). Wave w computes gate w (rows grouped i|f|g|o).
// Exchange: 8B words {tag32 | bf16 h(b+1) | bf16 h(b)} via relaxed agent
// atomics (data-embedded tags, verified protocol). Own-rank h short-circuits
// through LDS except at chunk starts.
// ---------------------------------------------------------------------------
__global__ __launch_bounds__(256, 1) void lstm_scan(
    const float* __restrict__ XF, const float* __restrict__ XB,
    const float* __restrict__ w_hh_f, const float* __restrict__ w_hh_b,
    float* __restrict__ hf, float* __restrict__ hb,
    unsigned long long* __restrict__ team_h,
    float* __restrict__ state_c, int t0, int t1)
{
    __shared__ unsigned short Ah[16][264];   // h as bf16: [batch(8 real+8 pad)][k=256]
    __shared__ float scr[4][64][9];          // MFMA out: [gate][unit][batch pad9]
    __shared__ float scx[4][8][68];          // X stage:  [gate][batch][unit pad68]

    const int blk  = blockIdx.x;      // 0..63
    const int team = blk >> 2;        // 0..15
    const int rank = blk & 3;         // 0..3
    const int dir  = team >> 3;
    const int bg   = team & 7;
    const int B0   = bg * 8;
    const float* __restrict__ X   = dir ? XB : XF;
    const float* __restrict__ Whh = dir ? w_hh_b : w_hh_f;
    float* __restrict__ Hout      = dir ? hb : hf;

    const int tid  = threadIdx.x;
    const int w    = tid >> 6;        // wave = gate
    const int lane = tid & 63;
    const int q    = lane >> 4;
    const int lr   = lane & 15;

    // register-resident bf16 W_hh B-fragments:
    // wave w, lane lr holds slice rows {w*64 + jt4*16 + lr}, k-slices q*8 within each 32
    short8 wreg[4][8];
    #pragma unroll
    for (int jt4 = 0; jt4 < 4; ++jt4) {
        const float* wrow = &Whh[(size_t)(w * 256 + rank * 64 + jt4 * 16 + lr) * 256];
        #pragma unroll
        for (int ks = 0; ks < 8; ++ks) {
            floatx4 a = *(const floatx4*)&wrow[ks * 32 + q * 8];
            floatx4 b = *(const floatx4*)&wrow[ks * 32 + q * 8 + 4];
            union { uint4 u; short8 s; } cv;
            cv.u = make_uint4(pk_bf16(a.x, a.y), pk_bf16(a.z, a.w),
                              pk_bf16(b.x, b.y), pk_bf16(b.z, b.w));
            wreg[jt4][ks] = cv.s;
        }
    }

    // phase-B mapping: thread owns unit u_p, batches {2*bq, 2*bq+1}
    const int u_p = tid & 63;
    const int bq  = tid >> 6;
    const int U   = rank * 64 + u_p;         // global unit of this thread's phase-B
    float c0 = 0.f, c1 = 0.f;
    const int sidx0 = team * 2048 + (bq * 2) * 256 + U;
    if (t0 > 0) { c0 = state_c[sidx0]; c1 = state_c[sidx0 + 256]; }

    unsigned long long* th = team_h + (size_t)team * 2048;  // [parity][U(256)][bpair(4)]

    // zero Ah padding rows (8-15); full zero at sequence start
    if (t0 == 0)
        for (int i = tid; i < 16 * 264; i += 256) ((unsigned short*)Ah)[i] = 0;
    else
        for (int i = tid; i < 8 * 264; i += 256) ((unsigned short*)Ah)[8 * 264 + i] = 0;

    for (int t = t0; t < t1; ++t) {
        // X prefetch (independent of h — in flight during the poll)
        float4 xr[2];
        int f4a = tid * 2, f4b = tid * 2 + 1;
        {
            int row = f4a >> 4, u4 = f4a & 15, g = row >> 3, b = row & 7;
            xr[0] = *(const float4*)&X[((size_t)(t - t0) * 64 + B0 + b) * 1024
                                       + g * 256 + rank * 64 + u4 * 4];
            row = f4b >> 4; u4 = f4b & 15; g = row >> 3; b = row & 7;
            xr[1] = *(const float4*)&X[((size_t)(t - t0) * 64 + B0 + b) * 1024
                                       + g * 256 + rank * 64 + u4 * 4];
        }

        // poll partner h (thread owns column U=tid); own-rank columns come
        // through LDS from phase B, except at chunk start (LDS not persistent)
        if (t > 0 && (t == t0 || (tid >> 6) != rank)) {
            const unsigned long long* src = th + ((size_t)((t - 1) & 1)) * 1024;
            unsigned long long v[4];
            #pragma unroll
            for (int p = 0; p < 4; ++p)
                v[p] = __hip_atomic_load(&src[tid * 4 + p], __ATOMIC_RELAXED,
                                         __HIP_MEMORY_SCOPE_AGENT);
            unsigned maskv = 0;
            int guard = 0;
            for (;;) {
                bool all = true;
                #pragma unroll
                for (int p = 0; p < 4; ++p) {
                    if (!((maskv >> p) & 1)) {
                        if ((unsigned)(v[p] >> 32) == (unsigned)t) {
                            maskv |= 1u << p;
                            unsigned w32 = (unsigned)v[p];
                            Ah[2 * p][tid]     = (unsigned short)(w32 & 0xffff);
                            Ah[2 * p + 1][tid] = (unsigned short)(w32 >> 16);
                        } else {
                            all = false;
                        }
                    }
                }
                if (all) break;
                if (++guard > (1 << 15)) {    // watchdog: fail loud, not hung
                    #pragma unroll
                    for (int p = 0; p < 4; ++p)
                        if (!((maskv >> p) & 1)) {
                            unsigned w32 = (unsigned)v[p];
                            Ah[2 * p][tid]     = (unsigned short)(w32 & 0xffff);
                            Ah[2 * p + 1][tid] = (unsigned short)(w32 >> 16);
                        }
                    break;
                }
                __builtin_amdgcn_s_sleep(1);
                #pragma unroll
                for (int p = 0; p < 4; ++p)
                    if (!((maskv >> p) & 1))
                        v[p] = __hip_atomic_load(&src[tid * 4 + p], __ATOMIC_RELAXED,
                                                 __HIP_MEMORY_SCOPE_AGENT);
            }
        }

        // stage X into LDS
        {
            int row = f4a >> 4, u4 = f4a & 15, g = row >> 3, b = row & 7;
            *(float4*)&scx[g][b][u4 * 4] = xr[0];
            row = f4b >> 4; u4 = f4b & 15; g = row >> 3; b = row & 7;
            *(float4*)&scx[g][b][u4 * 4] = xr[1];
        }
        __syncthreads();   // Ah + scx staged

        // phase A: MFMA — D[batch][slice row] = h[8x256] @ Whh_slice^T
        short8 af[8];
        #pragma unroll
        for (int ks = 0; ks < 8; ++ks)
            af[ks] = *(const short8*)&Ah[lr][ks * 32 + q * 8];
        #pragma unroll
        for (int jt4 = 0; jt4 < 4; ++jt4) {
            floatx4 c = {0.f, 0.f, 0.f, 0.f};
            #pragma unroll
            for (int ks = 0; ks < 8; ++ks)
                c = __builtin_amdgcn_mfma_f32_16x16x32_bf16(af[ks], wreg[jt4][ks], c, 0, 0, 0);
            if (q < 2) {     // batches 0..7 real (8..15 are zero padding)
                #pragma unroll
                for (int reg = 0; reg < 4; ++reg)
                    scr[w][jt4 * 16 + lr][q * 4 + reg] = c[reg];
            }
        }
        __syncthreads();   // scr ready

        // phase B: gates + state update, all 256 threads (2 (u,b) pairs each)
        {
            float h2[2];
            #pragma unroll
            for (int j = 0; j < 2; ++j) {
                int b = bq * 2 + j;
                float gi = scr[0][u_p][b] + scx[0][b][u_p];
                float gf = scr[1][u_p][b] + scx[1][b][u_p];
                float gg = scr[2][u_p][b] + scx[2][b][u_p];
                float go = scr[3][u_p][b] + scx[3][b][u_p];
                float ig = 1.f / (1.f + expf(-gi));
                float fg = 1.f / (1.f + expf(-gf));
                float gv = tanhf(gg);
                float og = 1.f / (1.f + expf(-go));
                float& cs = j ? c1 : c0;
                cs = fg * cs + ig * gv;
                float h = og * tanhf(cs);
                h2[j] = h;
                int tt = dir ? (511 - t) : t;
                Hout[((size_t)tt * 64 + B0 + b) * 256 + U] = h;
            }
            unsigned w32 = pk_bf16(h2[0], h2[1]);
            // own-rank short-circuit into LDS for next step's A
            Ah[2 * bq][U]     = (unsigned short)(w32 & 0xffff);
            Ah[2 * bq + 1][U] = (unsigned short)(w32 >> 16);
            unsigned long long pk =
                ((unsigned long long)(unsigned)(t + 1) << 32) | w32;
            __hip_atomic_store(&th[((size_t)(t & 1)) * 1024 + U * 4 + bq],
                               pk, __ATOMIC_RELAXED, __HIP_MEMORY_SCOPE_AGENT);
        }
        __syncthreads();   // all scr/scx/Ah reads done before next overwrite
    }

    state_c[sidx0] = c0;
    state_c[sidx0 + 256] = c1;
}

// ---------------------------------------------------------------------------
// Kernel 3: LayerNorm + classifier + argmax. One wave per (b,t).
// ---------------------------------------------------------------------------
__global__ __launch_bounds__(256) void ln_cls_kernel(
    const float* __restrict__ hf, const float* __restrict__ hb,
    const float* __restrict__ gamma, const float* __restrict__ beta,
    const float* __restrict__ cls_w, const float* __restrict__ cls_b,
    float* __restrict__ logits, float* __restrict__ dout)
{
    const int lane = threadIdx.x & 63;
    const int wid  = threadIdx.x >> 6;
    const int pos  = blockIdx.x * 4 + wid;   // 0..32767
    const int b = pos >> 9;
    const int t = pos & 511;

    float4 v0 = *(const float4*)&hf[((size_t)t * 64 + b) * 256 + lane * 4];
    float4 v1 = *(const float4*)&hb[((size_t)t * 64 + b) * 256 + lane * 4];
    float x[8] = {v0.x, v0.y, v0.z, v0.w, v1.x, v1.y, v1.z, v1.w};

    float s = 0.f;
    #pragma unroll
    for (int i = 0; i < 8; ++i) s += x[i];
    #pragma unroll
    for (int off = 32; off > 0; off >>= 1) s += __shfl_xor(s, off, 64);
    float mu = s * (1.f / 512.f);

    float d[8];
    float sq = 0.f;
    #pragma unroll
    for (int i = 0; i < 8; ++i) { d[i] = x[i] - mu; sq += d[i] * d[i]; }
    #pragma unroll
    for (int off = 32; off > 0; off >>= 1) sq += __shfl_xor(sq, off, 64);
    float rs = 1.f / sqrtf(sq * (1.f / 512.f) + 1e-5f);

    float4 g0  = *(const float4*)&gamma[lane * 4];
    float4 g1  = *(const float4*)&gamma[256 + lane * 4];
    float4 be0 = *(const float4*)&beta[lane * 4];
    float4 be1 = *(const float4*)&beta[256 + lane * 4];
    float y[8];
    y[0] = d[0] * rs * g0.x + be0.x; y[1] = d[1] * rs * g0.y + be0.y;
    y[2] = d[2] * rs * g0.z + be0.z; y[3] = d[3] * rs * g0.w + be0.w;
    y[4] = d[4] * rs * g1.x + be1.x; y[5] = d[5] * rs * g1.y + be1.y;
    y[6] = d[6] * rs * g1.z + be1.z; y[7] = d[7] * rs * g1.w + be1.w;

    float lgt[9];
    #pragma unroll
    for (int c = 0; c < 9; ++c) {
        float4 w0 = *(const float4*)&cls_w[c * 512 + lane * 4];
        float4 w1 = *(const float4*)&cls_w[c * 512 + 256 + lane * 4];
        float p = y[0] * w0.x + y[1] * w0.y + y[2] * w0.z + y[3] * w0.w
                + y[4] * w1.x + y[5] * w1.y + y[6] * w1.z + y[7] * w1.w;
        #pragma unroll
        for (int off = 32; off > 0; off >>= 1) p += __shfl_xor(p, off, 64);
        lgt[c] = p + cls_b[c];
    }
    if (lane == 0) {
        int bestc = 0;
        float bestv = lgt[0];
        #pragma unroll
        for (int c = 1; c < 9; ++c)
            if (lgt[c] > bestv) { bestv = lgt[c]; bestc = c; }  // strict >: first max
        dout[1 + pos] = (float)bestc;
        #pragma unroll
        for (int c = 0; c < 9; ++c) logits[(size_t)pos * 9 + c] = lgt[c];
    }
}

// ---------------------------------------------------------------------------
// Kernel 4: CRF numerator + forward algorithm (logZ). One wave per batch row.
// ---------------------------------------------------------------------------
__global__ __launch_bounds__(64) void crf_kernel(
    const float* __restrict__ logits, const int* __restrict__ label_ids,
    const float* __restrict__ crf_start, const float* __restrict__ crf_end,
    const float* __restrict__ crf_trans, float* __restrict__ llh)
{
    __shared__ float Ts[9][12];
    const int b = blockIdx.x;
    const int lane = threadIdx.x;
    if (lane < 81) Ts[lane / 9][lane % 9] = crf_trans[lane];
    __syncthreads();

    const float* __restrict__ em  = &logits[(size_t)b * 512 * 9];
    const int* __restrict__ tags  = &label_ids[b * 512];

    float part = 0.f;
    for (int t = lane; t < 512; t += 64) {
        int tg = tags[t];
        part += em[t * 9 + tg];
        if (t < 511) part += Ts[tg][tags[t + 1]];
    }
    #pragma unroll
    for (int off = 32; off > 0; off >>= 1) part += __shfl_xor(part, off, 64);
    float numer = part + crf_start[tags[0]] + crf_end[tags[511]];

    const int j = (lane < 9) ? lane : 0;
    float alpha = crf_start[j] + em[j];
    for (int t = 1; t < 512; ++t) {
        float av[9];
        float m = -1e30f;
        #pragma unroll
        for (int i = 0; i < 9; ++i) {
            float ai = __shfl(alpha, i, 64);
            av[i] = ai + Ts[i][j];
            m = fmaxf(m, av[i]);
        }
        float ssum = 0.f;
        #pragma unroll
        for (int i = 0; i < 9; ++i) ssum += expf(av[i] - m);
        alpha = m + logf(ssum) + em[t * 9 + j];
    }
    float v = (lane < 9) ? (alpha + crf_end[j]) : -1e30f;
    float mm = v;
    #pragma unroll
    for (int off = 32; off > 0; off >>= 1) mm = fmaxf(mm, __shfl_xor(mm, off, 64));
    float es = (lane < 9) ? expf(v - mm) : 0.f;
    #pragma unroll
    for (int off = 32; off > 0; off >>= 1) es += __shfl_xor(es, off, 64);
    if (lane == 0) llh[b] = numer - (mm + logf(es));
}

// ---------------------------------------------------------------------------
// Kernel 5: loss = -sum_b llh[b]
// ---------------------------------------------------------------------------
__global__ __launch_bounds__(64) void final_reduce(
    const float* __restrict__ llh, float* __restrict__ dout)
{
    float v = llh[threadIdx.x];
    #pragma unroll
    for (int off = 32; off > 0; off >>= 1) v += __shfl_xor(v, off, 64);
    if (threadIdx.x == 0) dout[0] = -v;
}

// ---------------------------------------------------------------------------
extern "C" void kernel_launch(void* const* d_in, const int* in_sizes, int n_in,
                              void* d_out, int out_size, void* d_ws, size_t ws_size,
                              hipStream_t stream)
{
    const int*   word_ids  = (const int*)d_in[0];
    const int*   label_ids = (const int*)d_in[1];
    const float* embed     = (const float*)d_in[2];
    const float* w_ih_f    = (const float*)d_in[3];
    const float* w_hh_f    = (const float*)d_in[4];
    const float* b_f       = (const float*)d_in[5];
    const float* w_ih_b    = (const float*)d_in[6];
    const float* w_hh_b    = (const float*)d_in[7];
    const float* b_b       = (const float*)d_in[8];
    const float* ln_gamma  = (const float*)d_in[9];
    const float* ln_beta   = (const float*)d_in[10];
    const float* cls_w     = (const float*)d_in[11];
    const float* cls_b     = (const float*)d_in[12];
    const float* crf_start = (const float*)d_in[13];
    const float* crf_end   = (const float*)d_in[14];
    const float* crf_trans = (const float*)d_in[15];

    char* w = (char*)d_ws;
    auto alloc = [&](size_t bytes) -> char* {
        char* p = w; w += (bytes + 255) & ~(size_t)255; return p;
    };
    float* hf      = (float*)alloc((size_t)8388608 * 4);   // [512][64][256]
    float* hb      = (float*)alloc((size_t)8388608 * 4);
    float* logits  = (float*)alloc((size_t)294912 * 4);    // [B*T][9]
    unsigned long long* team_h =
        (unsigned long long*)alloc((size_t)32768 * 8);     // 16 teams x 2 x 256U x 4bp
    float* state_c = (float*)alloc((size_t)32768 * 4);     // 16 teams x 8 x 256
    float* llh     = (float*)alloc((size_t)64 * 4);
    size_t fixed   = (size_t)(w - (char*)d_ws);

    // choose largest time-chunk L whose X buffers fit in the remaining ws
    int L = 512;
    while (L > 32 && fixed + (size_t)L * 524288 > ws_size) L >>= 1;
    float* XF = (float*)alloc((size_t)L * 65536 * 4);      // [L][64][1024]
    float* XB = (float*)alloc((size_t)L * 65536 * 4);
    int lgL = 31 - __builtin_clz((unsigned)L);

    // zero tags once per launch (tag 0 != any t+1 in 1..512)
    hipMemsetAsync(team_h, 0, (size_t)32768 * 8, stream);

    for (int t0 = 0; t0 < 512; t0 += L) {
        proj_kernel<<<dim3(16, L, 2), 256, 0, stream>>>(
            word_ids, embed, w_ih_f, b_f, w_ih_b, b_b, XF, XB, t0, lgL);
        lstm_scan<<<64, 256, 0, stream>>>(
            XF, XB, w_hh_f, w_hh_b, hf, hb, team_h, state_c, t0, t0 + L);
    }
    ln_cls_kernel<<<8192, 256, 0, stream>>>(
        hf, hb, ln_gamma, ln_beta, cls_w, cls_b, logits, (float*)d_out);
    crf_kernel<<<64, 64, 0, stream>>>(
        logits, label_ids, crf_start, crf_end, crf_trans, llh);
    final_reduce<<<1, 64, 0, stream>>>(llh, (float*)d_out);
}